// Round 2
// baseline (151573.743 us; speedup 1.0000x reference)
//
#include <hip/hip_runtime.h>
#include <math.h>

#define DEVINL __device__ __forceinline__

// ---------------------------------------------------------------------------
// RSSM scan, fully persistent: ONE kernel runs all T=64 steps. 256 WGs x 256
// threads (1 WG/CU; co-residency guaranteed). Phases chained via monotone
// device-scope counters. fp32 throughout (bf16 would flip argmaxes).
// GEMM producer: per-thread float4-W x 8-row register tile (32 FMA / 16B W
// load), A staged in LDS (broadcast b128 reads). Deterministic K-chunk slabs,
// finalizers do slab-sum + RMS + SiLU in one pass via LDS row buffer.
// ---------------------------------------------------------------------------

struct RPtrs {
  const float *embed, *action; const int *is_first;
  const float *W_in_deter, *b_in_deter, *g_in_deter;
  const float *W_in_stoch, *b_in_stoch, *g_in_stoch;
  const float *W_in_act,   *b_in_act,   *g_in_act;
  const float *W_dyn, *b_dyn, *g_dyn;
  const float *W_gru, *b_gru;
  const float *W_p0, *b_p0, *g_p0;
  const float *W_p1, *b_p1, *g_p1;
  const float *W_po, *b_po;
  const float *W_q0, *b_q0, *g_q0;
  const float *W_qo, *b_qo;
  float *out_post, *out_prior, *out_deters;
  float *deter, *determ, *xact, *hact, *p0act, *q0act, *p1act, *x12pre;
  float *R1, *R2, *R3, *stoch_scale;
  int *sidxg; unsigned *ctr;
};

DEVINL void waitc(unsigned* c, unsigned target) {
  if (threadIdx.x == 0) {
    while (__hip_atomic_load(c, __ATOMIC_RELAXED, __HIP_MEMORY_SCOPE_AGENT) < target)
      __builtin_amdgcn_s_sleep(8);
    (void)__hip_atomic_load(c, __ATOMIC_ACQUIRE, __HIP_MEMORY_SCOPE_AGENT);
  }
  __syncthreads();
}

DEVINL void arrive(unsigned* c) {
  __threadfence();
  __syncthreads();
  if (threadIdx.x == 0)
    __hip_atomic_fetch_add(c, 1u, __ATOMIC_RELEASE, __HIP_MEMORY_SCOPE_AGENT);
}

// ---- A loaders (return address of A[r][k]) --------------------------------
struct LdPlain {
  const float* A; int lda; int koff;
  DEVINL const float* addr(int r, int k) const { return A + (size_t)r * lda + koff + k; }
};
struct LdDyn {   // per-block: [dg(256, masked deter) | x(3072, activated)]
  const float* dm; const float* x; int blk;
  DEVINL const float* addr(int r, int k) const {
    return (k < 256) ? dm + (size_t)r * 2048 + blk * 256 + k
                     : x + (size_t)r * 3072 + (k - 256);
  }
};
struct LdQ0 {    // [deter(2048) | embed(1024)]
  const float* det; const float* emb; int t;
  DEVINL const float* addr(int r, int k) const {
    return (k < 2048) ? det + (size_t)r * 2048 + k
                      : emb + ((size_t)r * 64 + t) * 1024 + (k - 2048);
  }
};

#define FMA4(A, S, W4) { (A).x = fmaf((S), (W4).x, (A).x); (A).y = fmaf((S), (W4).y, (A).y); \
                         (A).z = fmaf((S), (W4).z, (A).z); (A).w = fmaf((S), (W4).w, (A).w); }

// ---- GEMM task: 32 rows x 256 cols x (NBLK*64) K. Writes slab[32][sst]. ----
template <int NBLK, typename LA>
DEVINL void gemm_task(LA la, const float* __restrict__ W, int ldw, int wcb,
                      int k0, float* __restrict__ slab, int sst, int scb,
                      const float* __restrict__ bias, float* As) {
  const int tid = threadIdx.x;
  const int cb = (tid & 63) * 4;   // 4 cols per thread, 256 cols per WG
  const int rg = tid >> 6;         // wave id -> rows rg*8 .. rg*8+7
  float4 acc[8];
#pragma unroll
  for (int i = 0; i < 8; ++i) acc[i] = make_float4(0.f, 0.f, 0.f, 0.f);

  // stage block 0 into LDS [kk][36] (pad keeps b128 reads aligned)
#pragma unroll
  for (int i = 0; i < 8; ++i) {
    int idx = tid + i * 256;
    As[(idx & 63) * 36 + (idx >> 6)] = *la.addr(idx >> 6, k0 + (idx & 63));
  }
  float nxt[8];
  if (NBLK == 2) {
#pragma unroll
    for (int i = 0; i < 8; ++i) {
      int idx = tid + i * 256;
      nxt[i] = *la.addr(idx >> 6, k0 + 64 + (idx & 63));
    }
  }
  __syncthreads();

#pragma unroll
  for (int b = 0; b < NBLK; ++b) {
    const float* Wp = W + (size_t)(k0 + b * 64) * ldw + wcb + cb;
    const float* Ab = As + b * 2304 + rg * 8;
#pragma unroll
    for (int kk = 0; kk < 64; ++kk) {
      float4 w   = *(const float4*)(Wp + (size_t)kk * ldw);
      float4 alo = *(const float4*)(Ab + kk * 36);
      float4 ahi = *(const float4*)(Ab + kk * 36 + 4);
      FMA4(acc[0], alo.x, w); FMA4(acc[1], alo.y, w);
      FMA4(acc[2], alo.z, w); FMA4(acc[3], alo.w, w);
      FMA4(acc[4], ahi.x, w); FMA4(acc[5], ahi.y, w);
      FMA4(acc[6], ahi.z, w); FMA4(acc[7], ahi.w, w);
    }
    if (NBLK == 2 && b == 0) {
#pragma unroll
      for (int i = 0; i < 8; ++i) {
        int idx = tid + i * 256;
        As[2304 + (idx & 63) * 36 + (idx >> 6)] = nxt[i];
      }
      __syncthreads();
    }
  }
  float4 badd = make_float4(0.f, 0.f, 0.f, 0.f);
  if (bias) badd = *(const float4*)(bias + wcb + cb);
#pragma unroll
  for (int i = 0; i < 8; ++i) {
    float4 v = acc[i];
    v.x += badd.x; v.y += badd.y; v.z += badd.z; v.w += badd.w;
    *(float4*)(slab + (size_t)(rg * 8 + i) * sst + scb + cb) = v;
  }
}

// ---- finalizer: y = sum chunks; rms; silu; one pass via LDS row buffer ----
DEVINL void act_fin(const float* __restrict__ slab, int N, int nch, int r,
                    const float* __restrict__ g, float* __restrict__ out,
                    float invN, float* smem) {
  const int tid = threadIdx.x;
  float* red = smem + 2048;
  float ss = 0.f;
  const int n4 = N >> 2;
  for (int i = tid; i < n4; i += 256) {
    float4 y = make_float4(0.f, 0.f, 0.f, 0.f);
    for (int ch = 0; ch < nch; ++ch) {
      float4 v = *(const float4*)(slab + ((size_t)ch * 32 + r) * N + (i << 2));
      y.x += v.x; y.y += v.y; y.z += v.z; y.w += v.w;
    }
    *(float4*)(smem + (i << 2)) = y;
    ss += y.x * y.x + y.y * y.y + y.z * y.z + y.w * y.w;
  }
#pragma unroll
  for (int o = 32; o > 0; o >>= 1) ss += __shfl_down(ss, o, 64);
  if ((tid & 63) == 0) red[tid >> 6] = ss;
  __syncthreads();
  if (tid == 0)
    red[4] = 1.f / sqrtf((red[0] + red[1] + red[2] + red[3]) * invN + 1e-6f);
  __syncthreads();
  const float sc = red[4];
  for (int i = tid; i < n4; i += 256) {
    float4 y = *(const float4*)(smem + (i << 2));
    float4 gg = *(const float4*)(g + (i << 2));
    float4 v;
    v.x = y.x * sc * gg.x; v.y = y.y * sc * gg.y;
    v.z = y.z * sc * gg.z; v.w = y.w * sc * gg.w;
    v.x = v.x / (1.f + expf(-v.x)); v.y = v.y / (1.f + expf(-v.y));
    v.z = v.z / (1.f + expf(-v.z)); v.w = v.w / (1.f + expf(-v.w));
    *(float4*)(out + (i << 2)) = v;
  }
  __syncthreads();
}

// ---- x1 (stoch one-hot gather) + x2 (action) pre-activations --------------
DEVINL void x12_body(const RPtrs& p, int t, int b8, float* smem) {
  float* sW2   = smem;               // [16][128]
  float* sa    = smem + 2048;        // [32][16]
  float* scoef = smem + 2560;        // [32]
  int*   sidx  = (int*)(smem + 2592);// [32][32]
  const int tid = threadIdx.x;
  const int cbase = b8 * 128;
  for (int i = tid; i < 1024; i += 256) sidx[i] = p.sidxg[i] & 31;
  for (int i = tid; i < 512; i += 256) {
    int r = i >> 4, ii = i & 15;
    float m = p.is_first[r * 64 + t] ? 0.f : 1.f;
    float v = p.action[((size_t)r * 64 + t) * 16 + ii] * m;
    sa[i] = v / fmaxf(fabsf(v), 1.f);
  }
  if (tid < 32) {
    float m = p.is_first[tid * 64 + t] ? 0.f : 1.f;
    scoef[tid] = m * p.stoch_scale[tid];
  }
  for (int i = tid; i < 2048; i += 256) {
    int ii = i >> 7, cc = i & 127;
    sW2[i] = p.W_in_act[ii * 1024 + cbase + cc];
  }
  __syncthreads();
  const int cc = tid & 127;
  for (int r = tid >> 7; r < 32; r += 2) {
    float coef = scoef[r];
    float s1 = 0.f;
    if (coef != 0.f) {
#pragma unroll
      for (int gg = 0; gg < 32; ++gg)
        s1 += p.W_in_stoch[((size_t)(gg * 32 + sidx[r * 32 + gg])) * 1024 + cbase + cc];
    }
    p.x12pre[(size_t)r * 1024 + cbase + cc] = p.b_in_stoch[cbase + cc] + coef * s1;
    float s2 = p.b_in_act[cbase + cc];
#pragma unroll
    for (int ii = 0; ii < 16; ++ii) s2 = fmaf(sa[r * 16 + ii], sW2[ii * 128 + cc], s2);
    p.x12pre[32768 + (size_t)r * 1024 + cbase + cc] = s2;
  }
  __syncthreads();
}

DEVINL float sigm(float x) { return 1.f / (1.f + expf(-x)); }

// ---- GRU finalizer: gates -> update; writes deter, determ(t+1), out -------
DEVINL void gru_fin(const RPtrs& p, int t, int r) {
  const int tid = threadIdx.x;
  const float* S = p.R3;  // gru gates slab [4][32][6144]
#pragma unroll
  for (int it = 0; it < 2; ++it) {
    int d0 = (tid + it * 256) * 4;
    int blk = d0 >> 8, j = d0 & 255;
    size_t base = (size_t)r * 6144 + blk * 768 + j;
    float4 ar = make_float4(0.f,0.f,0.f,0.f), ac = ar, au = ar;
#pragma unroll
    for (int ch = 0; ch < 4; ++ch) {
      const float* Sc = S + (size_t)ch * 196608 + base;
      float4 v0 = *(const float4*)(Sc);
      float4 v1 = *(const float4*)(Sc + 256);
      float4 v2 = *(const float4*)(Sc + 512);
      ar.x += v0.x; ar.y += v0.y; ar.z += v0.z; ar.w += v0.w;
      ac.x += v1.x; ac.y += v1.y; ac.z += v1.z; ac.w += v1.w;
      au.x += v2.x; au.y += v2.y; au.z += v2.z; au.w += v2.w;
    }
    float4 br = *(const float4*)(p.b_gru + blk * 768 + j);
    float4 bc = *(const float4*)(p.b_gru + blk * 768 + 256 + j);
    float4 bu = *(const float4*)(p.b_gru + blk * 768 + 512 + j);
    float4 dg = *(const float4*)(p.determ + (size_t)r * 2048 + d0);
    float mn = 0.f;
    if (t + 1 < 64) mn = p.is_first[r * 64 + t + 1] ? 0.f : 1.f;
    float4 nd;
    { float rs = sigm(ar.x + br.x); float cc2 = tanhf(rs * (ac.x + bc.x));
      float uu = sigm(au.x + bu.x - 1.f); nd.x = uu * cc2 + (1.f - uu) * dg.x; }
    { float rs = sigm(ar.y + br.y); float cc2 = tanhf(rs * (ac.y + bc.y));
      float uu = sigm(au.y + bu.y - 1.f); nd.y = uu * cc2 + (1.f - uu) * dg.y; }
    { float rs = sigm(ar.z + br.z); float cc2 = tanhf(rs * (ac.z + bc.z));
      float uu = sigm(au.z + bu.z - 1.f); nd.z = uu * cc2 + (1.f - uu) * dg.z; }
    { float rs = sigm(ar.w + br.w); float cc2 = tanhf(rs * (ac.w + bc.w));
      float uu = sigm(au.w + bu.w - 1.f); nd.w = uu * cc2 + (1.f - uu) * dg.w; }
    *(float4*)(p.deter + (size_t)r * 2048 + d0) = nd;
    *(float4*)(p.out_deters + ((size_t)r * 64 + t) * 2048 + d0) = nd;
    float4 nm; nm.x = nd.x * mn; nm.y = nd.y * mn; nm.z = nd.z * mn; nm.w = nd.w * mn;
    *(float4*)(p.determ + (size_t)r * 2048 + d0) = nm;
  }
}

DEVINL void po_fin(const RPtrs& p, int tpo, int r) {
  const int tid = threadIdx.x;
  const float* S = p.R3;  // po slab [16][32][1024]
  float4 y = make_float4(0.f, 0.f, 0.f, 0.f);
#pragma unroll
  for (int ch = 0; ch < 16; ++ch) {
    float4 v = *(const float4*)(S + ((size_t)ch * 32 + r) * 1024 + tid * 4);
    y.x += v.x; y.y += v.y; y.z += v.z; y.w += v.w;
  }
  *(float4*)(p.out_prior + ((size_t)r * 64 + tpo) * 1024 + tid * 4) = y;
}

DEVINL void qo_fin(const RPtrs& p, int t, int r, float* smem) {
  const int tid = threadIdx.x;
  const float* S = p.R1 + 524288;  // qo slab [16][32][1024]
  float4 y = make_float4(0.f, 0.f, 0.f, 0.f);
#pragma unroll
  for (int ch = 0; ch < 16; ++ch) {
    float4 v = *(const float4*)(S + ((size_t)ch * 32 + r) * 1024 + tid * 4);
    y.x += v.x; y.y += v.y; y.z += v.z; y.w += v.w;
  }
  *(float4*)(p.out_post + ((size_t)r * 64 + t) * 1024 + tid * 4) = y;
  *(float4*)(smem + tid * 4) = y;
  __syncthreads();
  if (tid < 32) {
    const float* rb = smem + tid * 32;
    float best = rb[0]; int bi = 0;
#pragma unroll
    for (int cc = 1; cc < 32; ++cc) {
      float v = rb[cc];
      if (v > best) { best = v; bi = cc; }   // strict > keeps first index
    }
    p.sidxg[r * 32 + tid] = bi;
    if (tid == 0) p.stoch_scale[r] = 1.f;
  }
  __syncthreads();
}

// ===========================================================================
__global__ __launch_bounds__(256, 2) void rssm_persist(RPtrs p) {
  const int wg = blockIdx.x;
  __shared__ __align__(16) float smem[4672];
  unsigned* cnt = p.ctr;

  for (int t = 0; t < 64; ++t) {
    // ---- P1: x0 (128) | po(t-1) (64) | x12 (8) = 200 tasks ----
    if (wg < 200) {
      waitc(cnt + 9, 64u * (unsigned)t);
      if (wg < 128) {                 // x0: KC=64, 32 kchunks x 4 coltiles
        int ct = wg & 3, kc = wg >> 2;
        LdPlain la{p.determ, 2048, 0};
        gemm_task<1>(la, p.W_in_deter, 1024, ct * 256, kc * 64,
                     p.R1 + (size_t)kc * 32768, 1024, ct * 256,
                     kc == 0 ? p.b_in_deter : nullptr, smem);
      } else if (wg < 192) {          // po(t-1): KC=64, 16 x 4
        if (t > 0) {
          int i = wg - 128, ct = i & 3, kc = i >> 2;
          LdPlain la{p.p1act, 1024, 0};
          gemm_task<1>(la, p.W_po, 1024, ct * 256, kc * 64,
                       p.R3 + (size_t)kc * 32768, 1024, ct * 256,
                       kc == 0 ? p.b_po : nullptr, smem);
        }
      } else {
        x12_body(p, t, wg - 192, smem);
      }
      arrive(cnt + 0);
    }
    // ---- P2: x0fin(32) x1fin(32) x2fin(32) pofin(32) ----
    if (wg < 128) {
      waitc(cnt + 0, 200u * (unsigned)(t + 1));
      int r = wg & 31;
      if (wg < 32)
        act_fin(p.R1, 1024, 32, r, p.g_in_deter, p.xact + (size_t)r * 3072, 1.f / 1024.f, smem);
      else if (wg < 64)
        act_fin(p.x12pre, 1024, 1, r, p.g_in_stoch, p.xact + (size_t)r * 3072 + 1024, 1.f / 1024.f, smem);
      else if (wg < 96)
        act_fin(p.x12pre + 32768, 1024, 1, r, p.g_in_act, p.xact + (size_t)r * 3072 + 2048, 1.f / 1024.f, smem);
      else { if (t > 0) po_fin(p, t - 1, r); }
      arrive(cnt + 1);
    }
    // ---- P3: dyn, KC=128, 26 chunks x 8 blocks = 208 ----
    if (wg < 208) {
      waitc(cnt + 1, 128u * (unsigned)(t + 1));
      int blk = wg / 26, kc = wg % 26;
      LdDyn la{p.determ, p.xact, blk};
      gemm_task<2>(la, p.W_dyn + (size_t)blk * 3328 * 256, 256, 0, kc * 128,
                   p.R2 + (size_t)kc * 65536, 2048, blk * 256,
                   kc == 0 ? p.b_dyn + blk * 256 : nullptr, smem);
      arrive(cnt + 2);
    }
    // ---- P4: dynfin (32) ----
    if (wg < 32) {
      waitc(cnt + 2, 208u * (unsigned)(t + 1));
      act_fin(p.R2, 2048, 26, wg, p.g_dyn, p.hact + (size_t)wg * 2048, 1.f / 2048.f, smem);
      arrive(cnt + 3);
    }
    // ---- P5: gru, KC=64, 4 chunks x 24 tiles = 96 ----
    if (wg < 96) {
      waitc(cnt + 3, 32u * (unsigned)(t + 1));
      int tile = wg >> 2, kc = wg & 3;
      int blk = tile / 3, g3 = tile % 3;
      LdPlain la{p.hact, 2048, blk * 256};
      gemm_task<1>(la, p.W_gru + (size_t)blk * 196608, 768, g3 * 256, kc * 64,
                   p.R3 + (size_t)kc * 196608, 6144, blk * 768 + g3 * 256,
                   kc == 0 ? p.b_gru + blk * 768 : nullptr, smem);
      arrive(cnt + 4);
    }
    // ---- P6: grufin (32) ----
    if (wg < 32) {
      waitc(cnt + 4, 96u * (unsigned)(t + 1));
      gru_fin(p, t, wg);
      arrive(cnt + 5);
    }
    // ---- P7: p0 (128, KC=64) + q0 (96, KC=128) = 224 ----
    if (wg < 224) {
      waitc(cnt + 5, 32u * (unsigned)(t + 1));
      if (wg < 128) {
        int ct = wg & 3, kc = wg >> 2;
        LdPlain la{p.deter, 2048, 0};
        gemm_task<1>(la, p.W_p0, 1024, ct * 256, kc * 64,
                     p.R2 + (size_t)kc * 32768, 1024, ct * 256,
                     kc == 0 ? p.b_p0 : nullptr, smem);
      } else {
        int i = wg - 128, ct = i & 3, kc = i >> 2;
        LdQ0 la{p.deter, p.embed, t};
        gemm_task<2>(la, p.W_q0, 1024, ct * 256, kc * 128,
                     p.R2 + 1048576 + (size_t)kc * 32768, 1024, ct * 256,
                     kc == 0 ? p.b_q0 : nullptr, smem);
      }
      arrive(cnt + 6);
    }
    // ---- P8: p0fin (32) + q0fin (32) ----
    if (wg < 64) {
      waitc(cnt + 6, 224u * (unsigned)(t + 1));
      int r = wg & 31;
      if (wg < 32)
        act_fin(p.R2, 1024, 32, r, p.g_p0, p.p0act + (size_t)r * 1024, 1.f / 1024.f, smem);
      else
        act_fin(p.R2 + 1048576, 1024, 24, r, p.g_q0, p.q0act + (size_t)r * 1024, 1.f / 1024.f, smem);
      arrive(cnt + 7);
    }
    // ---- P9: p1 (64, KC=64) + qo (64, KC=64) ----
    if (wg < 128) {
      waitc(cnt + 7, 64u * (unsigned)(t + 1));
      if (wg < 64) {
        int ct = wg & 3, kc = wg >> 2;
        LdPlain la{p.p0act, 1024, 0};
        gemm_task<1>(la, p.W_p1, 1024, ct * 256, kc * 64,
                     p.R1 + (size_t)kc * 32768, 1024, ct * 256,
                     kc == 0 ? p.b_p1 : nullptr, smem);
      } else {
        int i = wg - 64, ct = i & 3, kc = i >> 2;
        LdPlain la{p.q0act, 1024, 0};
        gemm_task<1>(la, p.W_qo, 1024, ct * 256, kc * 64,
                     p.R1 + 524288 + (size_t)kc * 32768, 1024, ct * 256,
                     kc == 0 ? p.b_qo : nullptr, smem);
      }
      arrive(cnt + 8);
    }
    // ---- P10: p1fin (32) + qofin (32) ----
    if (wg < 64) {
      waitc(cnt + 8, 128u * (unsigned)(t + 1));
      int r = wg & 31;
      if (wg < 32)
        act_fin(p.R1, 1024, 16, r, p.g_p1, p.p1act + (size_t)r * 1024, 1.f / 1024.f, smem);
      else
        qo_fin(p, t, r, smem);
      arrive(cnt + 9);
    }
  }

  // ---- tail: po for t=63 ----
  if (wg < 64) {
    waitc(cnt + 9, 64u * 64u);
    int ct = wg & 3, kc = wg >> 2;
    LdPlain la{p.p1act, 1024, 0};
    gemm_task<1>(la, p.W_po, 1024, ct * 256, kc * 64,
                 p.R3 + (size_t)kc * 32768, 1024, ct * 256,
                 kc == 0 ? p.b_po : nullptr, smem);
    arrive(cnt + 10);
  }
  if (wg < 32) {
    waitc(cnt + 10, 64u);
    po_fin(p, 63, wg);
  }
}

// ===========================================================================
extern "C" void kernel_launch(void* const* d_in, const int* in_sizes, int n_in,
                              void* d_out, int out_size, void* d_ws,
                              size_t ws_size, hipStream_t stream) {
  RPtrs p;
  p.embed      = (const float*)d_in[0];
  p.action     = (const float*)d_in[1];
  p.is_first   = (const int*)d_in[2];
  p.W_in_deter = (const float*)d_in[3];  p.b_in_deter = (const float*)d_in[4];  p.g_in_deter = (const float*)d_in[5];
  p.W_in_stoch = (const float*)d_in[6];  p.b_in_stoch = (const float*)d_in[7];  p.g_in_stoch = (const float*)d_in[8];
  p.W_in_act   = (const float*)d_in[9];  p.b_in_act   = (const float*)d_in[10]; p.g_in_act   = (const float*)d_in[11];
  p.W_dyn      = (const float*)d_in[12]; p.b_dyn      = (const float*)d_in[13]; p.g_dyn      = (const float*)d_in[14];
  p.W_gru      = (const float*)d_in[15]; p.b_gru      = (const float*)d_in[16];
  p.W_p0       = (const float*)d_in[17]; p.b_p0       = (const float*)d_in[18]; p.g_p0       = (const float*)d_in[19];
  p.W_p1       = (const float*)d_in[20]; p.b_p1       = (const float*)d_in[21]; p.g_p1       = (const float*)d_in[22];
  p.W_po       = (const float*)d_in[23]; p.b_po       = (const float*)d_in[24];
  p.W_q0       = (const float*)d_in[25]; p.b_q0       = (const float*)d_in[26]; p.g_q0       = (const float*)d_in[27];
  p.W_qo       = (const float*)d_in[28]; p.b_qo       = (const float*)d_in[29];

  float* o = (float*)d_out;
  p.out_post   = o;               // [32][64][1024]
  p.out_prior  = o + 2097152;     // [32][64][1024]
  p.out_deters = o + 4194304;     // [32][64][2048]

  float* w = (float*)d_ws;
  p.deter  = w;                   // 65536
  p.determ = w + 65536;           // 65536
  p.xact   = w + 131072;          // 98304  [32][3072]
  p.hact   = w + 229376;          // 65536
  p.p0act  = w + 294912;          // 32768
  p.q0act  = w + 327680;          // 32768
  p.p1act  = w + 360448;          // 32768
  p.x12pre = w + 393216;          // 65536  [2][32][1024]
  p.R1     = w + 458752;          // 1048576: x0(32ch) | p1(16ch)+qo(16ch)
  p.R2     = w + 1507328;         // 1835008: dyn(26ch) | p0(32ch)+q0(24ch)
  p.R3     = w + 3342336;         // 786432:  po(16ch)  | gru(4ch)
  p.stoch_scale = w + 4128768;    // 32
  p.sidxg  = (int*)(w + 4128800); // 1024
  p.ctr    = (unsigned*)(w + 4129824); // 16
  // total: 4129840 floats ~= 15.8 MB

  hipMemsetAsync(w, 0, 131072 * 4, stream);                // deter + determ
  hipMemsetAsync(w + 4128768, 0, 1072 * 4, stream);        // scale/sidx/ctr
  rssm_persist<<<256, 256, 0, stream>>>(p);
}

// Round 5
// 52053.784 us; speedup vs baseline: 2.9119x; 2.9119x over previous
//
#include <hip/hip_runtime.h>
#include <math.h>

#define DEVINL __device__ __forceinline__
typedef float f32x4 __attribute__((ext_vector_type(4)));

// ---------------------------------------------------------------------------
// RSSM scan, persistent single kernel. 256 WGs x 256 threads (all co-resident).
// R5: grid barrier between every phase (no hand-built dependence DAG), per-wave
// RELEASE arrives (vmcnt + buffer_wbl2, NO invalidates -> weights stay in L2),
// relaxed polling, sc0/sc1 loads/stores for all kernel-produced intermediates.
// Arithmetic replicates the R1 multi-launch kernel exactly (which passed at
// absmax 0.0078): same K-chunking (4 chunks/GEMM), same reduction orders.
// fp32 throughout (bf16 would flip argmaxes -> cascading recurrence error).
// ---------------------------------------------------------------------------

struct RPtrs {
  const float *embed, *action; const int *is_first;
  const float *W_in_deter, *b_in_deter, *g_in_deter;
  const float *W_in_stoch, *b_in_stoch, *g_in_stoch;
  const float *W_in_act,   *b_in_act,   *g_in_act;
  const float *W_dyn, *b_dyn, *g_dyn;
  const float *W_gru, *b_gru;
  const float *W_p0, *b_p0, *g_p0;
  const float *W_p1, *b_p1, *g_p1;
  const float *W_po, *b_po;
  const float *W_q0, *b_q0, *g_q0;
  const float *W_qo, *b_qo;
  float *out_post, *out_prior, *out_deters;
  float *deter, *determ, *xact, *hact, *p0act, *q0act, *p1act, *x12pre;
  float *Sx0, *Spo, *Sdyn, *Sp0, *Sq0, *Sp1, *Sqo;
  float *stoch_scale;
  int *sidxg; unsigned *gb;
};

// ---- sc0/sc1 (cross-XCD coherent) access helpers --------------------------
DEVINL void vm0() {
  asm volatile("s_waitcnt vmcnt(0)" ::: "memory");
  __builtin_amdgcn_sched_barrier(0);
}
DEVINL void ld2x4_issue(const float* p0, const float* p1, f32x4& r0, f32x4& r1) {
  asm volatile(
    "global_load_dwordx4 %0, %2, off sc0 sc1\n\t"
    "global_load_dwordx4 %1, %3, off sc0 sc1"
    : "=&v"(r0), "=&v"(r1) : "v"(p0), "v"(p1) : "memory");
}
DEVINL void ldsys4s(const float* p0, const float* p1, const float* p2, const float* p3,
                    float& r0, float& r1, float& r2, float& r3) {
  asm volatile(
    "global_load_dword %0, %4, off sc0 sc1\n\t"
    "global_load_dword %1, %5, off sc0 sc1\n\t"
    "global_load_dword %2, %6, off sc0 sc1\n\t"
    "global_load_dword %3, %7, off sc0 sc1\n\t"
    "s_waitcnt vmcnt(0)"
    : "=&v"(r0), "=&v"(r1), "=&v"(r2), "=&v"(r3)
    : "v"(p0), "v"(p1), "v"(p2), "v"(p3) : "memory");
}
DEVINL void ldsys4i(const int* p0, const int* p1, const int* p2, const int* p3,
                    int& r0, int& r1, int& r2, int& r3) {
  asm volatile(
    "global_load_dword %0, %4, off sc0 sc1\n\t"
    "global_load_dword %1, %5, off sc0 sc1\n\t"
    "global_load_dword %2, %6, off sc0 sc1\n\t"
    "global_load_dword %3, %7, off sc0 sc1\n\t"
    "s_waitcnt vmcnt(0)"
    : "=&v"(r0), "=&v"(r1), "=&v"(r2), "=&v"(r3)
    : "v"(p0), "v"(p1), "v"(p2), "v"(p3) : "memory");
}
DEVINL void ldsys8s(const float* p0, const float* p1, const float* p2, const float* p3,
                    const float* p4, const float* p5, const float* p6, const float* p7,
                    float& r0, float& r1, float& r2, float& r3,
                    float& r4, float& r5, float& r6, float& r7) {
  asm volatile(
    "global_load_dword %0, %8, off sc0 sc1\n\t"
    "global_load_dword %1, %9, off sc0 sc1\n\t"
    "global_load_dword %2, %10, off sc0 sc1\n\t"
    "global_load_dword %3, %11, off sc0 sc1\n\t"
    "global_load_dword %4, %12, off sc0 sc1\n\t"
    "global_load_dword %5, %13, off sc0 sc1\n\t"
    "global_load_dword %6, %14, off sc0 sc1\n\t"
    "global_load_dword %7, %15, off sc0 sc1\n\t"
    "s_waitcnt vmcnt(0)"
    : "=&v"(r0), "=&v"(r1), "=&v"(r2), "=&v"(r3),
      "=&v"(r4), "=&v"(r5), "=&v"(r6), "=&v"(r7)
    : "v"(p0), "v"(p1), "v"(p2), "v"(p3), "v"(p4), "v"(p5), "v"(p6), "v"(p7)
    : "memory");
}
DEVINL float ldsysf(const float* p) {
  float r;
  asm volatile("global_load_dword %0, %1, off sc0 sc1\n\ts_waitcnt vmcnt(0)"
               : "=&v"(r) : "v"(p) : "memory");
  return r;
}
DEVINL void stsysf(float* p, float v) {
  asm volatile("global_store_dword %0, %1, off sc0 sc1" :: "v"(p), "v"(v) : "memory");
}
DEVINL void stsysi(int* p, int v) {
  asm volatile("global_store_dword %0, %1, off sc0 sc1" :: "v"(p), "v"(v) : "memory");
}

// ---- grid barrier: per-wave RELEASE arrive, relaxed poll ------------------
// 32 slots x 64-u32 stride; each barrier adds 4 waves x 256 WGs = 1024.
DEVINL void gbar(unsigned* gb, unsigned idx) {
  vm0();                                      // this wave's sys-stores ack'd
  if ((threadIdx.x & 63) == 0)                // per-wave RELEASE (wbl2, no inv)
    __hip_atomic_fetch_add(gb + (blockIdx.x & 31) * 64, 1u,
                           __ATOMIC_RELEASE, __HIP_MEMORY_SCOPE_AGENT);
  __syncthreads();
  if (threadIdx.x == 0) {
    const unsigned target = idx * 1024u;
    for (;;) {
      unsigned s = 0;
#pragma unroll
      for (int i = 0; i < 32; ++i)
        s += __hip_atomic_load(gb + i * 64, __ATOMIC_RELAXED,
                               __HIP_MEMORY_SCOPE_AGENT);
      if (s >= target) break;
      __builtin_amdgcn_s_sleep(2);
    }
  }
  __syncthreads();
}

// ---- A loaders ------------------------------------------------------------
struct LdPlain {
  const float* A; int lda;
  DEVINL const float* addr(int r, int k) const { return A + (size_t)r * lda + k; }
};
struct LdDyn {   // [dg(256 masked deter) | x(3072 activated)]
  const float* dm; const float* x; int blk;
  DEVINL const float* addr(int r, int k) const {
    return (k < 256) ? dm + (size_t)r * 2048 + blk * 256 + k
                     : x + (size_t)r * 3072 + (k - 256);
  }
};
struct LdQ0 {    // [deter(2048) | embed(1024)]
  const float* det; const float* emb; int t;
  DEVINL const float* addr(int r, int k) const {
    return (k < 2048) ? det + (size_t)r * 2048 + k
                      : emb + ((size_t)r * 64 + t) * 1024 + (k - 2048);
  }
};

// ---- GEMM: 32 cols x 32 rows x (NBLK*64) K, acc carried across blocks -----
// Exactly R1's gemm_tile math: thread = 1 col x 4 rows, sequential kk.
template <int NBLK, typename LA>
DEVINL void gemm_tile(LA la, const float* __restrict__ W, int ldw, int wcb,
                      int k0, float* slab, int sst, int scb,
                      const float* __restrict__ bias, float* As) {
  const int tid = threadIdx.x;
  const int c = tid & 31;
  const int r0 = (tid >> 5) * 4;
  const int srr = tid >> 3;        // staging row 0..31
  const int skk = (tid & 7) * 8;   // staging k-offset in 64-block
  float a0 = 0.f, a1 = 0.f, a2 = 0.f, a3 = 0.f;
  f32x4 cur0 = {0,0,0,0}, cur1 = {0,0,0,0}, nxt0 = {0,0,0,0}, nxt1 = {0,0,0,0};
  {
    const float* ap = la.addr(srr, k0 + skk);
    ld2x4_issue(ap, ap + 4, cur0, cur1);
  }
  for (int b = 0; b < NBLK; ++b) {
    vm0();
    __syncthreads();               // all waves done computing previous block
#pragma unroll
    for (int e = 0; e < 4; ++e) {
      As[(skk + e) * 36 + srr]     = cur0[e];
      As[(skk + 4 + e) * 36 + srr] = cur1[e];
    }
    if (b + 1 < NBLK) {
      const float* ap = la.addr(srr, k0 + (b + 1) * 64 + skk);
      ld2x4_issue(ap, ap + 4, nxt0, nxt1);
    }
    __syncthreads();
    const float* Wp = W + (size_t)(k0 + b * 64) * ldw + wcb + c;
#pragma unroll 8
    for (int kk = 0; kk < 64; ++kk) {
      float w = Wp[(size_t)kk * ldw];               // plain (cached) W load
      const f32x4 av = *(const f32x4*)(As + kk * 36 + r0);
      a0 = fmaf(av[0], w, a0); a1 = fmaf(av[1], w, a1);
      a2 = fmaf(av[2], w, a2); a3 = fmaf(av[3], w, a3);
    }
    cur0 = nxt0; cur1 = nxt1;
  }
  if (bias) { float bv = bias[wcb + c]; a0 += bv; a1 += bv; a2 += bv; a3 += bv; }
  float* s = slab + (size_t)r0 * sst + scb + c;
  stsysf(s, a0);
  stsysf(s + sst, a1);
  stsysf(s + 2 * (size_t)sst, a2);
  stsysf(s + 3 * (size_t)sst, a3);
  __syncthreads();                 // smem free for a follow-on task this phase
}

// ---- finalizer: y = sum of <=4 chunks (seq), RMS, SiLU (R1 order) ---------
DEVINL void finalize_act(const float* slab, int sst, int nch, int r, int N,
                         const float* __restrict__ g, float* outrow,
                         float invN, float* smem) {
  const int tid = threadIdx.x;
  float* red = smem;
  float ss = 0.f;
  for (int c = tid; c < N; c += 256) {
    const float* b0 = slab + (size_t)r * sst + c;
    float v0, v1, v2, v3;
    ldsys4s(b0, b0 + (size_t)32 * sst, b0 + (size_t)64 * sst,
            b0 + (size_t)96 * sst, v0, v1, v2, v3);
    float y = v0;
    if (nch > 1) y += v1;
    if (nch > 2) y += v2;
    if (nch > 3) y += v3;
    ss += y * y;
  }
#pragma unroll
  for (int o = 32; o > 0; o >>= 1) ss += __shfl_down(ss, o, 64);
  if ((tid & 63) == 0) red[tid >> 6] = ss;
  __syncthreads();
  if (tid == 0)
    red[4] = 1.f / sqrtf((red[0] + red[1] + red[2] + red[3]) * invN + 1e-6f);
  __syncthreads();
  const float sc = red[4];
  for (int c = tid; c < N; c += 256) {
    const float* b0 = slab + (size_t)r * sst + c;
    float v0, v1, v2, v3;
    ldsys4s(b0, b0 + (size_t)32 * sst, b0 + (size_t)64 * sst,
            b0 + (size_t)96 * sst, v0, v1, v2, v3);
    float y = v0;
    if (nch > 1) y += v1;
    if (nch > 2) y += v2;
    if (nch > 3) y += v3;
    float v = y * sc * g[c];
    stsysf(outrow + c, v / (1.f + expf(-v)));
  }
  __syncthreads();
}

// ---- x1 (stoch one-hot gather) + x2 (action) pre-acts (R1 x12_body) -------
DEVINL void x12_body(const RPtrs& p, int t, int b8, float* smem) {
  float* sW2   = smem;                 // [16][128]
  float* sa    = smem + 2048;          // [32][16]
  float* scoef = smem + 2560;          // [32]
  int*   sidx  = (int*)(smem + 2592);  // [1024]
  const int tid = threadIdx.x;
  const int cb = b8 * 128;
  {
    int a, b, c, d;
    ldsys4i(p.sidxg + tid, p.sidxg + tid + 256, p.sidxg + tid + 512,
            p.sidxg + tid + 768, a, b, c, d);
    sidx[tid] = a & 31; sidx[tid + 256] = b & 31;
    sidx[tid + 512] = c & 31; sidx[tid + 768] = d & 31;
  }
  for (int i = tid; i < 512; i += 256) {
    int r = i >> 4, ii = i & 15;
    float m = p.is_first[r * 64 + t] ? 0.f : 1.f;
    float v = p.action[((size_t)r * 64 + t) * 16 + ii] * m;
    sa[i] = v / fmaxf(fabsf(v), 1.f);
  }
  if (tid < 32) {
    float m = p.is_first[tid * 64 + t] ? 0.f : 1.f;
    scoef[tid] = m * ldsysf(p.stoch_scale + tid);
  }
  for (int i = tid; i < 2048; i += 256)
    sW2[i] = p.W_in_act[(i >> 7) * 1024 + cb + (i & 127)];
  __syncthreads();
  const int c = tid & 127;
  for (int r = tid >> 7; r < 32; r += 2) {
    float coef = scoef[r];
    float s1 = 0.f;
    if (coef != 0.f) {
#pragma unroll
      for (int gg = 0; gg < 32; ++gg)
        s1 += p.W_in_stoch[(size_t)(gg * 32 + sidx[r * 32 + gg]) * 1024 + cb + c];
    }
    stsysf(p.x12pre + (size_t)r * 1024 + cb + c, p.b_in_stoch[cb + c] + coef * s1);
    float s2 = p.b_in_act[cb + c];
#pragma unroll
    for (int ii = 0; ii < 16; ++ii) s2 = fmaf(sa[r * 16 + ii], sW2[ii * 128 + c], s2);
    stsysf(p.x12pre + 32768 + (size_t)r * 1024 + cb + c, s2);
  }
  __syncthreads();
}

// ---- GRU fused (R1 L3): full K=256 dot + gate math + state update ---------
DEVINL void gru_body(const RPtrs& p, int t, int wg, float* Al) {
  const int blk = wg >> 4, jch = wg & 15;
  const int tid = threadIdx.x;
  {
    const float* hp = p.hact + blk * 256 + tid;
    for (int jb = 0; jb < 32; jb += 8) {
      float v0, v1, v2, v3, v4, v5, v6, v7;
      ldsys8s(hp + (size_t)(jb + 0) * 2048, hp + (size_t)(jb + 1) * 2048,
              hp + (size_t)(jb + 2) * 2048, hp + (size_t)(jb + 3) * 2048,
              hp + (size_t)(jb + 4) * 2048, hp + (size_t)(jb + 5) * 2048,
              hp + (size_t)(jb + 6) * 2048, hp + (size_t)(jb + 7) * 2048,
              v0, v1, v2, v3, v4, v5, v6, v7);
      Al[tid * 34 + jb + 0] = v0; Al[tid * 34 + jb + 1] = v1;
      Al[tid * 34 + jb + 2] = v2; Al[tid * 34 + jb + 3] = v3;
      Al[tid * 34 + jb + 4] = v4; Al[tid * 34 + jb + 5] = v5;
      Al[tid * 34 + jb + 6] = v6; Al[tid * 34 + jb + 7] = v7;
    }
  }
  __syncthreads();
  const int j = tid & 15, rg = tid >> 4;
  const int r0 = rg * 2;
  const int jcol = jch * 16 + j;
  const float* Wg = p.W_gru + (size_t)blk * 196608 + jcol;
  float r0a = 0, r1a = 0, c0a = 0, c1a = 0, u0a = 0, u1a = 0;
#pragma unroll 4
  for (int kk = 0; kk < 256; ++kk) {
    float wr = Wg[(size_t)kk * 768];
    float wc = Wg[(size_t)kk * 768 + 256];
    float wu = Wg[(size_t)kk * 768 + 512];
    float ax = Al[kk * 34 + r0], ay = Al[kk * 34 + r0 + 1];
    r0a = fmaf(ax, wr, r0a); r1a = fmaf(ay, wr, r1a);
    c0a = fmaf(ax, wc, c0a); c1a = fmaf(ay, wc, c1a);
    u0a = fmaf(ax, wu, u0a); u1a = fmaf(ay, wu, u1a);
  }
  const int col = blk * 256 + jcol;
  const float br = p.b_gru[blk * 768 + jcol];
  const float bc = p.b_gru[blk * 768 + 256 + jcol];
  const float bu = p.b_gru[blk * 768 + 512 + jcol];
#pragma unroll
  for (int rr = 0; rr < 2; ++rr) {
    int r = r0 + rr;
    float gr = (rr ? r1a : r0a) + br;
    float gc = (rr ? c1a : c0a) + bc;
    float gu = (rr ? u1a : u0a) + bu;
    float rs = 1.f / (1.f + expf(-gr));
    float cc = tanhf(rs * gc);
    float uu = 1.f / (1.f + expf(-(gu - 1.f)));
    float dg = ldsysf(p.determ + (size_t)r * 2048 + col);
    float nd = uu * cc + (1.f - uu) * dg;
    stsysf(p.deter + (size_t)r * 2048 + col, nd);
    p.out_deters[((size_t)r * 64 + t) * 2048 + col] = nd;
    float mn = 0.f;
    if (t + 1 < 64) mn = p.is_first[r * 64 + (t + 1)] ? 0.f : 1.f;
    stsysf(p.determ + (size_t)r * 2048 + col, nd * mn);
  }
}

// ---- output finalizers ----------------------------------------------------
DEVINL void pof_body(const RPtrs& p, int tpo, int r) {
  const int tid = threadIdx.x;
  for (int c = tid; c < 1024; c += 256) {
    const float* b0 = p.Spo + (size_t)r * 1024 + c;
    float v0, v1, v2, v3;
    ldsys4s(b0, b0 + 32768, b0 + 65536, b0 + 98304, v0, v1, v2, v3);
    p.out_prior[((size_t)r * 64 + tpo) * 1024 + c] = ((v0 + v1) + v2) + v3;
  }
}

DEVINL void qof_body(const RPtrs& p, int t, int r, float* smem) {
  const int tid = threadIdx.x;
  for (int c = tid; c < 1024; c += 256) {
    const float* b0 = p.Sqo + (size_t)r * 1024 + c;
    float v0, v1, v2, v3;
    ldsys4s(b0, b0 + 32768, b0 + 65536, b0 + 98304, v0, v1, v2, v3);
    float y = ((v0 + v1) + v2) + v3;
    p.out_post[((size_t)r * 64 + t) * 1024 + c] = y;
    smem[c] = y;
  }
  __syncthreads();
  if (tid < 32) {
    const float* rb = smem + tid * 32;
    float best = rb[0]; int bi = 0;
#pragma unroll
    for (int cc = 1; cc < 32; ++cc) {
      float v = rb[cc];
      if (v > best) { best = v; bi = cc; }   // strict > keeps first index
    }
    stsysi(p.sidxg + r * 32 + tid, bi);
    if (tid == 0) stsysf(p.stoch_scale + r, 1.f);
  }
  __syncthreads();
}

// ===========================================================================
__global__ __launch_bounds__(256, 2) void rssm_persist(RPtrs p) {
  const int wg = blockIdx.x;
  __shared__ __align__(16) float smem[8706];
  unsigned bidx = 0;

  for (int t = 0; t < 64; ++t) {
    // P1: x0 (0-127) | po(t-1) (128-255) | x12 (248-255, second task)
    if (wg < 128) {
      int nch = wg & 31, kc = wg >> 5;
      LdPlain la{p.determ, 2048};
      gemm_tile<8>(la, p.W_in_deter, 1024, nch * 32, kc * 512,
                   p.Sx0 + (size_t)kc * 32768, 1024, nch * 32,
                   kc == 0 ? p.b_in_deter : nullptr, smem);
    } else {
      if (t > 0) {
        int i = wg - 128, nch = i & 31, kc = i >> 5;
        LdPlain la{p.p1act, 1024};
        gemm_tile<4>(la, p.W_po, 1024, nch * 32, kc * 256,
                     p.Spo + (size_t)kc * 32768, 1024, nch * 32,
                     kc == 0 ? p.b_po : nullptr, smem);
      }
      if (wg >= 248) x12_body(p, t, wg - 248, smem);
    }
    gbar(p.gb, ++bidx);
    // P2: x0fin (0-31) | x1fin (32-63) | x2fin (64-95) | pofin(t-1) (96-127)
    if (wg < 32)
      finalize_act(p.Sx0, 1024, 4, wg, 1024, p.g_in_deter,
                   p.xact + (size_t)wg * 3072, 1.f / 1024.f, smem);
    else if (wg < 64)
      finalize_act(p.x12pre, 1024, 1, wg - 32, 1024, p.g_in_stoch,
                   p.xact + (size_t)(wg - 32) * 3072 + 1024, 1.f / 1024.f, smem);
    else if (wg < 96)
      finalize_act(p.x12pre + 32768, 1024, 1, wg - 64, 1024, p.g_in_act,
                   p.xact + (size_t)(wg - 64) * 3072 + 2048, 1.f / 1024.f, smem);
    else if (wg < 128) {
      if (t > 0) pof_body(p, t - 1, wg - 96);
    }
    gbar(p.gb, ++bidx);
    // P3: dyn (all 256): 8 blk x 8 coltiles x 4 kc, KC=832
    {
      int blk = wg >> 5, i = wg & 31, nch = i & 7, kc = i >> 3;
      LdDyn la{p.determ, p.xact, blk};
      gemm_tile<13>(la, p.W_dyn + (size_t)blk * 851968, 256, nch * 32, kc * 832,
                    p.Sdyn + (size_t)kc * 65536, 2048, blk * 256 + nch * 32,
                    kc == 0 ? p.b_dyn + blk * 256 : nullptr, smem);
    }
    gbar(p.gb, ++bidx);
    // P4: dynfin (0-31)
    if (wg < 32)
      finalize_act(p.Sdyn, 2048, 4, wg, 2048, p.g_dyn,
                   p.hact + (size_t)wg * 2048, 1.f / 2048.f, smem);
    gbar(p.gb, ++bidx);
    // P5: gru fused (0-127)
    if (wg < 128) gru_body(p, t, wg, smem);
    gbar(p.gb, ++bidx);
    // P6: p0 (0-127) | q0 (128-255)
    if (wg < 128) {
      int nch = wg & 31, kc = wg >> 5;
      LdPlain la{p.deter, 2048};
      gemm_tile<8>(la, p.W_p0, 1024, nch * 32, kc * 512,
                   p.Sp0 + (size_t)kc * 32768, 1024, nch * 32,
                   kc == 0 ? p.b_p0 : nullptr, smem);
    } else {
      int i = wg - 128, nch = i & 31, kc = i >> 5;
      LdQ0 la{p.deter, p.embed, t};
      gemm_tile<12>(la, p.W_q0, 1024, nch * 32, kc * 768,
                    p.Sq0 + (size_t)kc * 32768, 1024, nch * 32,
                    kc == 0 ? p.b_q0 : nullptr, smem);
    }
    gbar(p.gb, ++bidx);
    // P7: p0fin (0-31) | q0fin (32-63)
    if (wg < 32)
      finalize_act(p.Sp0, 1024, 4, wg, 1024, p.g_p0,
                   p.p0act + (size_t)wg * 1024, 1.f / 1024.f, smem);
    else if (wg < 64)
      finalize_act(p.Sq0, 1024, 4, wg - 32, 1024, p.g_q0,
                   p.q0act + (size_t)(wg - 32) * 1024, 1.f / 1024.f, smem);
    gbar(p.gb, ++bidx);
    // P8: p1 (0-127) | qo (128-255)
    if (wg < 128) {
      int nch = wg & 31, kc = wg >> 5;
      LdPlain la{p.p0act, 1024};
      gemm_tile<4>(la, p.W_p1, 1024, nch * 32, kc * 256,
                   p.Sp1 + (size_t)kc * 32768, 1024, nch * 32,
                   kc == 0 ? p.b_p1 : nullptr, smem);
    } else {
      int i = wg - 128, nch = i & 31, kc = i >> 5;
      LdPlain la{p.q0act, 1024};
      gemm_tile<4>(la, p.W_qo, 1024, nch * 32, kc * 256,
                   p.Sqo + (size_t)kc * 32768, 1024, nch * 32,
                   kc == 0 ? p.b_qo : nullptr, smem);
    }
    gbar(p.gb, ++bidx);
    // P9: p1fin (0-31) | qofin+argmax (32-63)
    if (wg < 32)
      finalize_act(p.Sp1, 1024, 4, wg, 1024, p.g_p1,
                   p.p1act + (size_t)wg * 1024, 1.f / 1024.f, smem);
    else if (wg < 64)
      qof_body(p, t, wg - 32, smem);
    gbar(p.gb, ++bidx);
  }

  // tail: po(63)
  if (wg < 128) {
    int nch = wg & 31, kc = wg >> 5;
    LdPlain la{p.p1act, 1024};
    gemm_tile<4>(la, p.W_po, 1024, nch * 32, kc * 256,
                 p.Spo + (size_t)kc * 32768, 1024, nch * 32,
                 kc == 0 ? p.b_po : nullptr, smem);
  }
  gbar(p.gb, ++bidx);
  if (wg < 32) pof_body(p, 63, wg);
}

// ===========================================================================
extern "C" void kernel_launch(void* const* d_in, const int* in_sizes, int n_in,
                              void* d_out, int out_size, void* d_ws,
                              size_t ws_size, hipStream_t stream) {
  RPtrs p;
  p.embed      = (const float*)d_in[0];
  p.action     = (const float*)d_in[1];
  p.is_first   = (const int*)d_in[2];
  p.W_in_deter = (const float*)d_in[3];  p.b_in_deter = (const float*)d_in[4];  p.g_in_deter = (const float*)d_in[5];
  p.W_in_stoch = (const float*)d_in[6];  p.b_in_stoch = (const float*)d_in[7];  p.g_in_stoch = (const float*)d_in[8];
  p.W_in_act   = (const float*)d_in[9];  p.b_in_act   = (const float*)d_in[10]; p.g_in_act   = (const float*)d_in[11];
  p.W_dyn      = (const float*)d_in[12]; p.b_dyn      = (const float*)d_in[13]; p.g_dyn      = (const float*)d_in[14];
  p.W_gru      = (const float*)d_in[15]; p.b_gru      = (const float*)d_in[16];
  p.W_p0       = (const float*)d_in[17]; p.b_p0       = (const float*)d_in[18]; p.g_p0       = (const float*)d_in[19];
  p.W_p1       = (const float*)d_in[20]; p.b_p1       = (const float*)d_in[21]; p.g_p1       = (const float*)d_in[22];
  p.W_po       = (const float*)d_in[23]; p.b_po       = (const float*)d_in[24];
  p.W_q0       = (const float*)d_in[25]; p.b_q0       = (const float*)d_in[26]; p.g_q0       = (const float*)d_in[27];
  p.W_qo       = (const float*)d_in[28]; p.b_qo       = (const float*)d_in[29];

  float* o = (float*)d_out;
  p.out_post   = o;               // [32][64][1024]
  p.out_prior  = o + 2097152;     // [32][64][1024]
  p.out_deters = o + 4194304;     // [32][64][2048]

  float* w = (float*)d_ws;
  p.deter  = w;                   // 65536
  p.determ = w + 65536;           // 65536
  p.xact   = w + 131072;          // 98304   [32][3072]
  p.hact   = w + 229376;          // 65536
  p.p0act  = w + 294912;          // 32768
  p.q0act  = w + 327680;          // 32768
  p.p1act  = w + 360448;          // 32768
  p.x12pre = w + 393216;          // 65536   [2][32][1024]
  p.Sx0    = w + 458752;          // 131072  [4][32][1024]
  p.Spo    = w + 589824;          // 131072
  p.Sdyn   = w + 720896;          // 262144  [4][32][2048]
  p.Sp0    = w + 983040;          // 131072
  p.Sq0    = w + 1114112;         // 131072
  p.Sp1    = w + 1245184;         // 131072
  p.Sqo    = w + 1376256;         // 131072
  p.stoch_scale = w + 1507328;    // 32
  p.sidxg  = (int*)(w + 1507360); // 1024
  p.gb     = (unsigned*)(w + 1508384); // 32 slots x 64 u32 = 2048
  // total 1510432 floats ~= 6.04 MB

  hipMemsetAsync(w, 0, 131072 * 4, stream);            // deter + determ
  hipMemsetAsync(w + 1507328, 0, 3104 * 4, stream);    // scale/sidx/gbar
  rssm_persist<<<256, 256, 0, stream>>>(p);
}

// Round 8
// 9142.352 us; speedup vs baseline: 16.5793x; 5.6937x over previous
//
#include <hip/hip_runtime.h>
#include <math.h>

#define DEVINL __device__ __forceinline__
typedef float f32x4 __attribute__((ext_vector_type(4)));

// ---------------------------------------------------------------------------
// RSSM scan, multi-launch (8 kernels/step + prologue/tail = 516 launches).
// Launch boundaries provide all cross-WG ordering/coherence (R1 architecture,
// which passed) -- NO in-kernel cross-WG sync, no sc0/sc1, no atomics.
// Learned R5 vs R7: vmcnt-ack of sc0sc1 stores != L3 visibility; only a
// wbl2-release orders them, at ~85us/barrier -> persistent sync is a dead end.
// GEMM: 256-col x 32-row tiles, f32x4 W loads (32 FMA/16B), wave-uniform LDS
// broadcast A reads, conflict-free staging, double-buffered K-blocks.
// fp32 throughout (bf16 would flip argmaxes -> cascading recurrence error).
// ---------------------------------------------------------------------------

struct RPtrs {
  const float *embed, *action; const int *is_first;
  const float *W_in_deter, *b_in_deter, *g_in_deter;
  const float *W_in_stoch, *b_in_stoch, *g_in_stoch;
  const float *W_in_act,   *b_in_act,   *g_in_act;
  const float *W_dyn, *b_dyn, *g_dyn;
  const float *W_gru, *b_gru;
  const float *W_p0, *b_p0, *g_p0;
  const float *W_p1, *b_p1, *g_p1;
  const float *W_po, *b_po;
  const float *W_q0, *b_q0, *g_q0;
  const float *W_qo, *b_qo;
  float *out_post, *out_prior, *out_deters;
  float *deter, *determ, *xact, *hact, *p0act, *q0act, *p1act;
  float *SlabA, *SlabB, *SlabC, *SlabD;
  float *stoch_scale;
  int *sidxg;
};

// ---- A loaders ------------------------------------------------------------
struct LdPlain {
  const float* A; int lda;
  DEVINL const float* addr(int r, int k) const { return A + (size_t)r * lda + k; }
};
struct LdDyn {   // [dg(256 masked deter) | x(3072 activated)]
  const float* dm; const float* x; int blk;
  DEVINL const float* addr(int r, int k) const {
    return (k < 256) ? dm + (size_t)r * 2048 + blk * 256 + k
                     : x + (size_t)r * 3072 + (k - 256);
  }
};
struct LdQ0 {    // [deter(2048) | embed(1024)]
  const float* det; const float* emb; int t;
  DEVINL const float* addr(int r, int k) const {
    return (k < 2048) ? det + (size_t)r * 2048 + k
                      : emb + ((size_t)r * 64 + t) * 1024 + (k - 2048);
  }
};

#define FMA4(A, S, W) { (A)[0]=fmaf((S),(W)[0],(A)[0]); (A)[1]=fmaf((S),(W)[1],(A)[1]); \
                        (A)[2]=fmaf((S),(W)[2],(A)[2]); (A)[3]=fmaf((S),(W)[3],(A)[3]); }

// ---- GEMM: one WG = 256 cols x 32 rows x (NBLK*64) K ----------------------
// Thread = 4 cols (f32x4 W load) x its wave's 8 rows (LDS broadcast).
template <int NBLK, typename LA>
DEVINL void gemm_tile(LA la, const float* __restrict__ W, int ldw, int wcb,
                      int k0, float* __restrict__ slab, int sst, int scb,
                      const float* __restrict__ bias, float* As) {
  const int tid = threadIdx.x;
  const int c4 = (tid & 63) * 4;
  const int rg = (tid >> 6) * 8;
  const int srr = tid & 31;
  const int skk = (tid >> 5) * 8;
  f32x4 acc[8];
#pragma unroll
  for (int i = 0; i < 8; ++i) acc[i] = (f32x4){0.f, 0.f, 0.f, 0.f};
  const float* ap = la.addr(srr, k0 + skk);
  f32x4 cur0 = *(const f32x4*)ap;
  f32x4 cur1 = *(const f32x4*)(ap + 4);
#pragma unroll
  for (int b = 0; b < NBLK; ++b) {
    __syncthreads();               // prev block's As fully consumed
#pragma unroll
    for (int e = 0; e < 4; ++e) {
      As[(skk + e) * 36 + srr]     = cur0[e];
      As[(skk + 4 + e) * 36 + srr] = cur1[e];
    }
    f32x4 nxt0, nxt1;
    if (b + 1 < NBLK) {
      const float* np = la.addr(srr, k0 + (b + 1) * 64 + skk);
      nxt0 = *(const f32x4*)np;
      nxt1 = *(const f32x4*)(np + 4);
    }
    __syncthreads();
    const float* Wp = W + (size_t)(k0 + b * 64) * ldw + wcb + c4;
#pragma unroll 8
    for (int kk = 0; kk < 64; ++kk) {
      f32x4 w = *(const f32x4*)(Wp + (size_t)kk * ldw);   // L2-cached, coalesced
      const float* Ab = As + kk * 36 + rg;                // wave-uniform bcast
      f32x4 alo = *(const f32x4*)(Ab);
      f32x4 ahi = *(const f32x4*)(Ab + 4);
      FMA4(acc[0], alo[0], w); FMA4(acc[1], alo[1], w);
      FMA4(acc[2], alo[2], w); FMA4(acc[3], alo[3], w);
      FMA4(acc[4], ahi[0], w); FMA4(acc[5], ahi[1], w);
      FMA4(acc[6], ahi[2], w); FMA4(acc[7], ahi[3], w);
    }
    if (b + 1 < NBLK) { cur0 = nxt0; cur1 = nxt1; }
  }
  f32x4 bv = (f32x4){0.f, 0.f, 0.f, 0.f};
  if (bias) bv = *(const f32x4*)(bias + wcb + c4);
#pragma unroll
  for (int i = 0; i < 8; ++i) {
    f32x4 o = acc[i] + bv;
    *(f32x4*)(slab + (size_t)(rg + i) * sst + scb + c4) = o;
  }
}

// ---- finalizer: y = sum chunks (regs, ascending), RMS, SiLU ---------------
DEVINL void act_fin(const float* __restrict__ slab, int N, int nch, int r,
                    const float* __restrict__ g, float* __restrict__ out,
                    float invN, float* red) {
  const int tid = threadIdx.x;
  const size_t cstr = (size_t)32 * N;
  const float* base = slab + (size_t)r * N + tid * 4;
  f32x4 y0 = (f32x4){0.f, 0.f, 0.f, 0.f}, y1 = y0;
  for (int ch = 0; ch < nch; ++ch)
    y0 += *(const f32x4*)(base + (size_t)ch * cstr);
  float ss = y0[0]*y0[0] + y0[1]*y0[1] + y0[2]*y0[2] + y0[3]*y0[3];
  if (N == 2048) {
    for (int ch = 0; ch < nch; ++ch)
      y1 += *(const f32x4*)(base + 1024 + (size_t)ch * cstr);
    ss += y1[0]*y1[0] + y1[1]*y1[1] + y1[2]*y1[2] + y1[3]*y1[3];
  }
#pragma unroll
  for (int o = 32; o > 0; o >>= 1) ss += __shfl_down(ss, o, 64);
  if ((tid & 63) == 0) red[tid >> 6] = ss;
  __syncthreads();
  if (tid == 0)
    red[4] = 1.f / sqrtf((red[0] + red[1] + red[2] + red[3]) * invN + 1e-6f);
  __syncthreads();
  const float sc = red[4];
  {
    f32x4 gg = *(const f32x4*)(g + tid * 4);
    f32x4 v = y0 * sc * gg;
#pragma unroll
    for (int k = 0; k < 4; ++k) v[k] = v[k] / (1.f + expf(-v[k]));
    *(f32x4*)(out + tid * 4) = v;
  }
  if (N == 2048) {
    f32x4 gg = *(const f32x4*)(g + 1024 + tid * 4);
    f32x4 v = y1 * sc * gg;
#pragma unroll
    for (int k = 0; k < 4; ++k) v[k] = v[k] / (1.f + expf(-v[k]));
    *(f32x4*)(out + 1024 + tid * 4) = v;
  }
}

// ---- x1 (stoch gather) + x2 (action): full compute + RMS + SiLU per wave --
DEVINL void x12_full(const RPtrs& p, int t, int wgid) {
  const int tid = threadIdx.x;
  const int w = tid >> 6, lane = tid & 63;
  const int r = wgid * 4 + w;
  const float m = p.is_first[r * 64 + t] ? 0.f : 1.f;
  const float coef = m * p.stoch_scale[r];
  int idxv = 0;
  if (lane < 32) idxv = p.sidxg[r * 32 + lane] & 31;
  const int c0 = lane * 4;
  // ---- x1
  f32x4 s1[4];
#pragma unroll
  for (int j = 0; j < 4; ++j) s1[j] = (f32x4){0.f, 0.f, 0.f, 0.f};
  if (coef != 0.f) {
    for (int g = 0; g < 32; ++g) {
      int ig = __shfl(idxv, g, 64);
      const float* row = p.W_in_stoch + (size_t)(g * 32 + ig) * 1024 + c0;
#pragma unroll
      for (int j = 0; j < 4; ++j) s1[j] += *(const f32x4*)(row + j * 256);
    }
  }
  float ss = 0.f;
  f32x4 pre1[4];
#pragma unroll
  for (int j = 0; j < 4; ++j) {
    f32x4 b = *(const f32x4*)(p.b_in_stoch + c0 + j * 256);
    f32x4 v = b + s1[j] * coef;
    pre1[j] = v;
    ss += v[0]*v[0] + v[1]*v[1] + v[2]*v[2] + v[3]*v[3];
  }
#pragma unroll
  for (int o = 32; o > 0; o >>= 1) ss += __shfl_down(ss, o, 64);
  ss = __shfl(ss, 0, 64);
  float sc = 1.f / sqrtf(ss * (1.f / 1024.f) + 1e-6f);
#pragma unroll
  for (int j = 0; j < 4; ++j) {
    f32x4 gg = *(const f32x4*)(p.g_in_stoch + c0 + j * 256);
    f32x4 v = pre1[j] * sc * gg;
#pragma unroll
    for (int k = 0; k < 4; ++k) v[k] = v[k] / (1.f + expf(-v[k]));
    *(f32x4*)(p.xact + (size_t)r * 3072 + 1024 + c0 + j * 256) = v;
  }
  // ---- x2
  float av[16];
  const float* arow = p.action + ((size_t)r * 64 + t) * 16;
#pragma unroll
  for (int ii = 0; ii < 16; ++ii) {
    float vv = arow[ii] * m;
    av[ii] = vv / fmaxf(fabsf(vv), 1.f);
  }
  f32x4 s2[4];
#pragma unroll
  for (int j = 0; j < 4; ++j) s2[j] = *(const f32x4*)(p.b_in_act + c0 + j * 256);
#pragma unroll
  for (int ii = 0; ii < 16; ++ii) {
    const float* wrow = p.W_in_act + ii * 1024 + c0;
#pragma unroll
    for (int j = 0; j < 4; ++j) {
      f32x4 wv = *(const f32x4*)(wrow + j * 256);
      FMA4(s2[j], av[ii], wv);
    }
  }
  ss = 0.f;
#pragma unroll
  for (int j = 0; j < 4; ++j)
    ss += s2[j][0]*s2[j][0] + s2[j][1]*s2[j][1] + s2[j][2]*s2[j][2] + s2[j][3]*s2[j][3];
#pragma unroll
  for (int o = 32; o > 0; o >>= 1) ss += __shfl_down(ss, o, 64);
  ss = __shfl(ss, 0, 64);
  sc = 1.f / sqrtf(ss * (1.f / 1024.f) + 1e-6f);
#pragma unroll
  for (int j = 0; j < 4; ++j) {
    f32x4 gg = *(const f32x4*)(p.g_in_act + c0 + j * 256);
    f32x4 v = s2[j] * sc * gg;
#pragma unroll
    for (int k = 0; k < 4; ++k) v[k] = v[k] / (1.f + expf(-v[k]));
    *(f32x4*)(p.xact + (size_t)r * 3072 + 2048 + c0 + j * 256) = v;
  }
}

// ---- output finalizers (16 chunks) ----------------------------------------
DEVINL void pof_body(const RPtrs& p, int tpo, int r) {
  const int tid = threadIdx.x;
  const float* b0 = p.SlabC + (size_t)r * 1024 + tid * 4;
  f32x4 y = (f32x4){0.f, 0.f, 0.f, 0.f};
#pragma unroll
  for (int ch = 0; ch < 16; ++ch) y += *(const f32x4*)(b0 + (size_t)ch * 32768);
  *(f32x4*)(p.out_prior + ((size_t)r * 64 + tpo) * 1024 + tid * 4) = y;
}

DEVINL void qof_body(const RPtrs& p, int t, int r, float* smem) {
  const int tid = threadIdx.x;
  const float* b0 = p.SlabA + 524288 + (size_t)r * 1024 + tid * 4;
  f32x4 y = (f32x4){0.f, 0.f, 0.f, 0.f};
#pragma unroll
  for (int ch = 0; ch < 16; ++ch) y += *(const f32x4*)(b0 + (size_t)ch * 32768);
  *(f32x4*)(p.out_post + ((size_t)r * 64 + t) * 1024 + tid * 4) = y;
  *(f32x4*)(smem + tid * 4) = y;
  __syncthreads();
  if (tid < 32) {
    const float* rb = smem + tid * 32;
    float best = rb[0]; int bi = 0;
#pragma unroll
    for (int cc = 1; cc < 32; ++cc) {
      float v = rb[cc];
      if (v > best) { best = v; bi = cc; }   // strict > keeps first index
    }
    p.sidxg[r * 32 + tid] = bi;
    if (tid == 0) p.stoch_scale[r] = 1.f;
  }
}

DEVINL float sigm(float x) { return 1.f / (1.f + expf(-x)); }

// ===========================================================================
// K0: init state
__global__ __launch_bounds__(256) void k_init(RPtrs p) {
  size_t i = (size_t)blockIdx.x * 256 + threadIdx.x;
  if (i < 65536) { p.deter[i] = 0.f; p.determ[i] = 0.f; }
  if (i < 1024) p.sidxg[i] = 0;
  if (i < 32) p.stoch_scale[i] = 0.f;
}

// prologue x0(0): grid 64
__global__ __launch_bounds__(256, 2) void k_x0(RPtrs p) {
  __shared__ __align__(16) float As[2304];
  int ct = blockIdx.x & 3, kc = blockIdx.x >> 2;
  LdPlain la{p.determ, 2048};
  gemm_tile<2>(la, p.W_in_deter, 1024, ct * 256, kc * 128,
               p.SlabD + (size_t)kc * 32768, 1024, ct * 256,
               kc == 0 ? p.b_in_deter : nullptr, As);
}
// prologue x0fin: grid 32
__global__ __launch_bounds__(256, 2) void k_x0fin(RPtrs p) {
  __shared__ float red[8];
  act_fin(p.SlabD, 1024, 16, blockIdx.x, p.g_in_deter,
          p.xact + (size_t)blockIdx.x * 3072, 1.f / 1024.f, red);
}

// K1: x12 (64-71) + po(t-1) (0-63). grid 72
__global__ __launch_bounds__(256, 2) void k_x12_po(RPtrs p, int t) {
  __shared__ __align__(16) float As[2304];
  const int wg = blockIdx.x;
  if (wg < 64) {
    if (t == 0) return;
    int ct = wg & 3, kc = wg >> 2;   // KC=64
    LdPlain la{p.p1act, 1024};
    gemm_tile<1>(la, p.W_po, 1024, ct * 256, kc * 64,
                 p.SlabC + (size_t)kc * 32768, 1024, ct * 256,
                 kc == 0 ? p.b_po : nullptr, As);
  } else {
    x12_full(p, t, wg - 64);
  }
}

// K2: dyn (0-207) + pofin(t-1) (208-239). grid 240
__global__ __launch_bounds__(256, 2) void k_dyn(RPtrs p, int t) {
  __shared__ __align__(16) float As[2304];
  const int wg = blockIdx.x;
  if (wg < 208) {
    int blk = wg / 26, kc = wg % 26;  // KC=128
    LdDyn la{p.determ, p.xact, blk};
    gemm_tile<2>(la, p.W_dyn + (size_t)blk * 851968, 256, 0, kc * 128,
                 p.SlabB + (size_t)kc * 65536, 2048, blk * 256,
                 kc == 0 ? p.b_dyn + blk * 256 : nullptr, As);
  } else {
    if (t > 0) pof_body(p, t - 1, wg - 208);
  }
}

// K3: dynfin. grid 32
__global__ __launch_bounds__(256, 2) void k_dynfin(RPtrs p) {
  __shared__ float red[8];
  act_fin(p.SlabB, 2048, 26, blockIdx.x, p.g_dyn,
          p.hact + (size_t)blockIdx.x * 2048, 1.f / 2048.f, red);
}

// K4: gru. grid 128
__global__ __launch_bounds__(256, 2) void k_gru(RPtrs p, int t) {
  __shared__ float Al[8704];
  const int wg = blockIdx.x;
  const int blk = wg >> 4, jch = wg & 15;
  const int tid = threadIdx.x;
  {
    const float* hp = p.hact + blk * 256 + tid;
#pragma unroll
    for (int jb = 0; jb < 32; ++jb)
      Al[tid * 34 + jb] = hp[(size_t)jb * 2048];
  }
  __syncthreads();
  const int j = tid & 15, rg = tid >> 4;
  const int r0 = rg * 2;
  const int jcol = jch * 16 + j;
  const float* Wg = p.W_gru + (size_t)blk * 196608 + jcol;
  float r0a = 0, r1a = 0, c0a = 0, c1a = 0, u0a = 0, u1a = 0;
#pragma unroll 4
  for (int kk = 0; kk < 256; ++kk) {
    float wr = Wg[(size_t)kk * 768];
    float wc = Wg[(size_t)kk * 768 + 256];
    float wu = Wg[(size_t)kk * 768 + 512];
    float ax = Al[kk * 34 + r0], ay = Al[kk * 34 + r0 + 1];
    r0a = fmaf(ax, wr, r0a); r1a = fmaf(ay, wr, r1a);
    c0a = fmaf(ax, wc, c0a); c1a = fmaf(ay, wc, c1a);
    u0a = fmaf(ax, wu, u0a); u1a = fmaf(ay, wu, u1a);
  }
  const int col = blk * 256 + jcol;
  const float br = p.b_gru[blk * 768 + jcol];
  const float bc = p.b_gru[blk * 768 + 256 + jcol];
  const float bu = p.b_gru[blk * 768 + 512 + jcol];
#pragma unroll
  for (int rr = 0; rr < 2; ++rr) {
    int r = r0 + rr;
    float gr = (rr ? r1a : r0a) + br;
    float gc = (rr ? c1a : c0a) + bc;
    float gu = (rr ? u1a : u0a) + bu;
    float rs = sigm(gr);
    float cc = tanhf(rs * gc);
    float uu = sigm(gu - 1.f);
    float dg = p.determ[(size_t)r * 2048 + col];
    float nd = uu * cc + (1.f - uu) * dg;
    p.deter[(size_t)r * 2048 + col] = nd;
    p.out_deters[((size_t)r * 64 + t) * 2048 + col] = nd;
    float mn = 0.f;
    if (t + 1 < 64) mn = p.is_first[r * 64 + (t + 1)] ? 0.f : 1.f;
    p.determ[(size_t)r * 2048 + col] = nd * mn;
  }
}

// K5: p0 (0-63) + q0 (64-159) + x0(t+1) (160-223). grid 224
__global__ __launch_bounds__(256, 2) void k_pq(RPtrs p, int t) {
  __shared__ __align__(16) float As[2304];
  const int wg = blockIdx.x;
  if (wg < 64) {
    int ct = wg & 3, kc = wg >> 2;   // KC=128
    LdPlain la{p.deter, 2048};
    gemm_tile<2>(la, p.W_p0, 1024, ct * 256, kc * 128,
                 p.SlabB + (size_t)kc * 32768, 1024, ct * 256,
                 kc == 0 ? p.b_p0 : nullptr, As);
  } else if (wg < 160) {
    int i = wg - 64, ct = i & 3, kc = i >> 2;   // kc 0..23, KC=128
    LdQ0 la{p.deter, p.embed, t};
    gemm_tile<2>(la, p.W_q0, 1024, ct * 256, kc * 128,
                 p.SlabB + 524288 + (size_t)kc * 32768, 1024, ct * 256,
                 kc == 0 ? p.b_q0 : nullptr, As);
  } else {
    if (t >= 63) return;
    int i = wg - 160, ct = i & 3, kc = i >> 2;
    LdPlain la{p.determ, 2048};
    gemm_tile<2>(la, p.W_in_deter, 1024, ct * 256, kc * 128,
                 p.SlabD + (size_t)kc * 32768, 1024, ct * 256,
                 kc == 0 ? p.b_in_deter : nullptr, As);
  }
}

// K6: p0fin (0-31) + q0fin (32-63) + x0fin(t+1) (64-95). grid 96
__global__ __launch_bounds__(256, 2) void k_pqfin(RPtrs p, int t) {
  __shared__ float red[8];
  const int wg = blockIdx.x;
  if (wg < 32)
    act_fin(p.SlabB, 1024, 16, wg, p.g_p0, p.p0act + (size_t)wg * 1024,
            1.f / 1024.f, red);
  else if (wg < 64)
    act_fin(p.SlabB + 524288, 1024, 24, wg - 32, p.g_q0,
            p.q0act + (size_t)(wg - 32) * 1024, 1.f / 1024.f, red);
  else {
    if (t >= 63) return;
    act_fin(p.SlabD, 1024, 16, wg - 64, p.g_in_deter,
            p.xact + (size_t)(wg - 64) * 3072, 1.f / 1024.f, red);
  }
}

// K7: p1 (0-63) + qo (64-127). grid 128
__global__ __launch_bounds__(256, 2) void k_p1qo(RPtrs p, int t) {
  __shared__ __align__(16) float As[2304];
  const int wg = blockIdx.x;
  if (wg < 64) {
    int ct = wg & 3, kc = wg >> 2;   // KC=64
    LdPlain la{p.p0act, 1024};
    gemm_tile<1>(la, p.W_p1, 1024, ct * 256, kc * 64,
                 p.SlabA + (size_t)kc * 32768, 1024, ct * 256,
                 kc == 0 ? p.b_p1 : nullptr, As);
  } else {
    int i = wg - 64, ct = i & 3, kc = i >> 2;   // KC=64
    LdPlain la{p.q0act, 1024};
    gemm_tile<1>(la, p.W_qo, 1024, ct * 256, kc * 64,
                 p.SlabA + 524288 + (size_t)kc * 32768, 1024, ct * 256,
                 kc == 0 ? p.b_qo : nullptr, As);
  }
}

// K8: p1fin (0-31) + qofin+argmax (32-63). grid 64
__global__ __launch_bounds__(256, 2) void k_fin2(RPtrs p, int t) {
  __shared__ __align__(16) float smem[1032];
  const int wg = blockIdx.x;
  if (wg < 32)
    act_fin(p.SlabA, 1024, 16, wg, p.g_p1, p.p1act + (size_t)wg * 1024,
            1.f / 1024.f, smem);
  else
    qof_body(p, t, wg - 32, smem);
}

// tail: po(63). grid 64
__global__ __launch_bounds__(256, 2) void k_po63(RPtrs p) {
  __shared__ __align__(16) float As[2304];
  int ct = blockIdx.x & 3, kc = blockIdx.x >> 2;
  LdPlain la{p.p1act, 1024};
  gemm_tile<1>(la, p.W_po, 1024, ct * 256, kc * 64,
               p.SlabC + (size_t)kc * 32768, 1024, ct * 256,
               kc == 0 ? p.b_po : nullptr, As);
}
// tail: pofin(63). grid 32
__global__ __launch_bounds__(256, 2) void k_pofin63(RPtrs p) {
  pof_body(p, 63, blockIdx.x);
}

// ===========================================================================
extern "C" void kernel_launch(void* const* d_in, const int* in_sizes, int n_in,
                              void* d_out, int out_size, void* d_ws,
                              size_t ws_size, hipStream_t stream) {
  RPtrs p;
  p.embed      = (const float*)d_in[0];
  p.action     = (const float*)d_in[1];
  p.is_first   = (const int*)d_in[2];
  p.W_in_deter = (const float*)d_in[3];  p.b_in_deter = (const float*)d_in[4];  p.g_in_deter = (const float*)d_in[5];
  p.W_in_stoch = (const float*)d_in[6];  p.b_in_stoch = (const float*)d_in[7];  p.g_in_stoch = (const float*)d_in[8];
  p.W_in_act   = (const float*)d_in[9];  p.b_in_act   = (const float*)d_in[10]; p.g_in_act   = (const float*)d_in[11];
  p.W_dyn      = (const float*)d_in[12]; p.b_dyn      = (const float*)d_in[13]; p.g_dyn      = (const float*)d_in[14];
  p.W_gru      = (const float*)d_in[15]; p.b_gru      = (const float*)d_in[16];
  p.W_p0       = (const float*)d_in[17]; p.b_p0       = (const float*)d_in[18]; p.g_p0       = (const float*)d_in[19];
  p.W_p1       = (const float*)d_in[20]; p.b_p1       = (const float*)d_in[21]; p.g_p1       = (const float*)d_in[22];
  p.W_po       = (const float*)d_in[23]; p.b_po       = (const float*)d_in[24];
  p.W_q0       = (const float*)d_in[25]; p.b_q0       = (const float*)d_in[26]; p.g_q0       = (const float*)d_in[27];
  p.W_qo       = (const float*)d_in[28]; p.b_qo       = (const float*)d_in[29];

  float* o = (float*)d_out;
  p.out_post   = o;               // [32][64][1024]
  p.out_prior  = o + 2097152;     // [32][64][1024]
  p.out_deters = o + 4194304;     // [32][64][2048]

  float* w = (float*)d_ws;
  p.deter  = w;                   // 65536
  p.determ = w + 65536;           // 65536
  p.xact   = w + 131072;          // 98304   [32][3072]
  p.hact   = w + 229376;          // 65536
  p.p0act  = w + 294912;          // 32768
  p.q0act  = w + 327680;          // 32768
  p.p1act  = w + 360448;          // 32768
  p.SlabA  = w + 393216;          // 1048576: p1(16ch)@0 | qo(16ch)@524288
  p.SlabB  = w + 1441792;         // 1703936: dyn(26ch) | p0(16ch)@0 + q0(24ch)@524288
  p.SlabC  = w + 3145728;         // 524288:  po(16ch)
  p.SlabD  = w + 3670016;         // 524288:  x0(16ch)
  p.stoch_scale = w + 4194304;    // 32
  p.sidxg  = (int*)(w + 4194336); // 1024
  // total ~16.8 MB

  k_init<<<256, 256, 0, stream>>>(p);
  k_x0<<<64, 256, 0, stream>>>(p);
  k_x0fin<<<32, 256, 0, stream>>>(p);
  for (int t = 0; t < 64; ++t) {
    k_x12_po<<<72, 256, 0, stream>>>(p, t);
    k_dyn<<<240, 256, 0, stream>>>(p, t);
    k_dynfin<<<32, 256, 0, stream>>>(p);
    k_gru<<<128, 256, 0, stream>>>(p, t);
    k_pq<<<224, 256, 0, stream>>>(p, t);
    k_pqfin<<<96, 256, 0, stream>>>(p, t);
    k_p1qo<<<128, 256, 0, stream>>>(p, t);
    k_fin2<<<64, 256, 0, stream>>>(p, t);
  }
  k_po63<<<64, 256, 0, stream>>>(p);
  k_pofin63<<<32, 256, 0, stream>>>(p);
}

// Round 9
// 7257.419 us; speedup vs baseline: 20.8854x; 1.2597x over previous
//
#include <hip/hip_runtime.h>
#include <math.h>

#define DEVINL __device__ __forceinline__
typedef float f32x4 __attribute__((ext_vector_type(4)));

// ---------------------------------------------------------------------------
// RSSM scan, multi-launch (7 kernels/step + 3 prologue + 5 epilogue = 456).
// Launch boundaries provide all cross-WG ordering (R8 architecture, passed).
// R9: (1) prior chain (p0->p1->po) moved OUT of the t-loop: batched M=2048
// GEMMs over out_deters after the scan (it never feeds the recurrence).
// (2) x12(t+1) fused into the argmax kernel (uses in-smem argmax directly).
// GEMM: 256-col x 32-row tiles, f32x4 W loads (32 FMA/16B), wave-uniform LDS
// broadcast A reads, conflict-free staging, double-buffered K-blocks.
// fp32 throughout (bf16 would flip argmaxes -> cascading recurrence error).
// ---------------------------------------------------------------------------

struct RPtrs {
  const float *embed, *action; const int *is_first;
  const float *W_in_deter, *b_in_deter, *g_in_deter;
  const float *W_in_stoch, *b_in_stoch, *g_in_stoch;
  const float *W_in_act,   *b_in_act,   *g_in_act;
  const float *W_dyn, *b_dyn, *g_dyn;
  const float *W_gru, *b_gru;
  const float *W_p0, *b_p0, *g_p0;
  const float *W_p1, *b_p1, *g_p1;
  const float *W_po, *b_po;
  const float *W_q0, *b_q0, *g_q0;
  const float *W_qo, *b_qo;
  float *out_post, *out_prior, *out_deters;
  float *deter, *determ, *xact, *hact, *q0act;
  float *SDyn, *SQ0, *SX0, *SQO, *Abuf0, *Abuf1;
};

// ---- A loaders ------------------------------------------------------------
struct LdPlain {
  const float* A; int lda;
  DEVINL const float* addr(int r, int k) const { return A + (size_t)r * lda + k; }
};
struct LdDyn {   // [dg(256 masked deter) | x(3072 activated)]
  const float* dm; const float* x; int blk;
  DEVINL const float* addr(int r, int k) const {
    return (k < 256) ? dm + (size_t)r * 2048 + blk * 256 + k
                     : x + (size_t)r * 3072 + (k - 256);
  }
};
struct LdQ0 {    // [deter(2048) | embed(1024)]
  const float* det; const float* emb; int t;
  DEVINL const float* addr(int r, int k) const {
    return (k < 2048) ? det + (size_t)r * 2048 + k
                      : emb + ((size_t)r * 64 + t) * 1024 + (k - 2048);
  }
};

#define FMA4(A, S, W) { (A)[0]=fmaf((S),(W)[0],(A)[0]); (A)[1]=fmaf((S),(W)[1],(A)[1]); \
                        (A)[2]=fmaf((S),(W)[2],(A)[2]); (A)[3]=fmaf((S),(W)[3],(A)[3]); }

// ---- GEMM (K-chunked, slab output): 256 cols x 32 rows x (NBLK*64) K ------
template <int NBLK, typename LA>
DEVINL void gemm_tile(LA la, const float* __restrict__ W, int ldw, int wcb,
                      int k0, float* __restrict__ slab, int sst, int scb,
                      const float* __restrict__ bias, float* As) {
  const int tid = threadIdx.x;
  const int c4 = (tid & 63) * 4;
  const int rg = (tid >> 6) * 8;
  const int srr = tid & 31;
  const int skk = (tid >> 5) * 8;
  f32x4 acc[8];
#pragma unroll
  for (int i = 0; i < 8; ++i) acc[i] = (f32x4){0.f, 0.f, 0.f, 0.f};
  const float* ap = la.addr(srr, k0 + skk);
  f32x4 cur0 = *(const f32x4*)ap;
  f32x4 cur1 = *(const f32x4*)(ap + 4);
#pragma unroll
  for (int b = 0; b < NBLK; ++b) {
    __syncthreads();
#pragma unroll
    for (int e = 0; e < 4; ++e) {
      As[(skk + e) * 36 + srr]     = cur0[e];
      As[(skk + 4 + e) * 36 + srr] = cur1[e];
    }
    f32x4 nxt0, nxt1;
    if (b + 1 < NBLK) {
      const float* np = la.addr(srr, k0 + (b + 1) * 64 + skk);
      nxt0 = *(const f32x4*)np;
      nxt1 = *(const f32x4*)(np + 4);
    }
    __syncthreads();
    const float* Wp = W + (size_t)(k0 + b * 64) * ldw + wcb + c4;
#pragma unroll 8
    for (int kk = 0; kk < 64; ++kk) {
      f32x4 w = *(const f32x4*)(Wp + (size_t)kk * ldw);
      const float* Ab = As + kk * 36 + rg;
      f32x4 alo = *(const f32x4*)(Ab);
      f32x4 ahi = *(const f32x4*)(Ab + 4);
      FMA4(acc[0], alo[0], w); FMA4(acc[1], alo[1], w);
      FMA4(acc[2], alo[2], w); FMA4(acc[3], alo[3], w);
      FMA4(acc[4], ahi[0], w); FMA4(acc[5], ahi[1], w);
      FMA4(acc[6], ahi[2], w); FMA4(acc[7], ahi[3], w);
    }
    if (b + 1 < NBLK) { cur0 = nxt0; cur1 = nxt1; }
  }
  f32x4 bv = (f32x4){0.f, 0.f, 0.f, 0.f};
  if (bias) bv = *(const f32x4*)(bias + wcb + c4);
#pragma unroll
  for (int i = 0; i < 8; ++i) {
    f32x4 o = acc[i] + bv;
    *(f32x4*)(slab + (size_t)(rg + i) * sst + scb + c4) = o;
  }
}

// ---- GEMM (full-K, direct output + bias): for batched epilogue ------------
template <typename LA>
DEVINL void gemm_big(LA la, const float* __restrict__ W, int ldw, int wcb,
                     int nblk, float* __restrict__ outp, int ost,
                     const float* __restrict__ bias, float* As) {
  const int tid = threadIdx.x;
  const int c4 = (tid & 63) * 4;
  const int rg = (tid >> 6) * 8;
  const int srr = tid & 31;
  const int skk = (tid >> 5) * 8;
  f32x4 acc[8];
#pragma unroll
  for (int i = 0; i < 8; ++i) acc[i] = (f32x4){0.f, 0.f, 0.f, 0.f};
  const float* ap = la.addr(srr, skk);
  f32x4 cur0 = *(const f32x4*)ap;
  f32x4 cur1 = *(const f32x4*)(ap + 4);
  f32x4 nxt0, nxt1;
  for (int b = 0; b < nblk; ++b) {
    __syncthreads();
#pragma unroll
    for (int e = 0; e < 4; ++e) {
      As[(skk + e) * 36 + srr]     = cur0[e];
      As[(skk + 4 + e) * 36 + srr] = cur1[e];
    }
    if (b + 1 < nblk) {
      const float* np = la.addr(srr, (b + 1) * 64 + skk);
      nxt0 = *(const f32x4*)np;
      nxt1 = *(const f32x4*)(np + 4);
    }
    __syncthreads();
    const float* Wp = W + (size_t)(b * 64) * ldw + wcb + c4;
#pragma unroll 8
    for (int kk = 0; kk < 64; ++kk) {
      f32x4 w = *(const f32x4*)(Wp + (size_t)kk * ldw);
      const float* Ab = As + kk * 36 + rg;
      f32x4 alo = *(const f32x4*)(Ab);
      f32x4 ahi = *(const f32x4*)(Ab + 4);
      FMA4(acc[0], alo[0], w); FMA4(acc[1], alo[1], w);
      FMA4(acc[2], alo[2], w); FMA4(acc[3], alo[3], w);
      FMA4(acc[4], ahi[0], w); FMA4(acc[5], ahi[1], w);
      FMA4(acc[6], ahi[2], w); FMA4(acc[7], ahi[3], w);
    }
    if (b + 1 < nblk) { cur0 = nxt0; cur1 = nxt1; }
  }
  f32x4 bv = *(const f32x4*)(bias + wcb + c4);
#pragma unroll
  for (int i = 0; i < 8; ++i) {
    f32x4 o = acc[i] + bv;
    *(f32x4*)(outp + (size_t)(rg + i) * ost + wcb + c4) = o;
  }
}

// ---- finalizer: y = sum chunks (regs, ascending), RMS, SiLU ---------------
DEVINL void act_fin(const float* __restrict__ slab, int N, int nch, int r,
                    const float* __restrict__ g, float* __restrict__ out,
                    float invN, float* red) {
  const int tid = threadIdx.x;
  const size_t cstr = (size_t)32 * N;
  const float* base = slab + (size_t)r * N + tid * 4;
  f32x4 y0 = (f32x4){0.f, 0.f, 0.f, 0.f}, y1 = y0;
  for (int ch = 0; ch < nch; ++ch)
    y0 += *(const f32x4*)(base + (size_t)ch * cstr);
  float ss = y0[0]*y0[0] + y0[1]*y0[1] + y0[2]*y0[2] + y0[3]*y0[3];
  if (N == 2048) {
    for (int ch = 0; ch < nch; ++ch)
      y1 += *(const f32x4*)(base + 1024 + (size_t)ch * cstr);
    ss += y1[0]*y1[0] + y1[1]*y1[1] + y1[2]*y1[2] + y1[3]*y1[3];
  }
#pragma unroll
  for (int o = 32; o > 0; o >>= 1) ss += __shfl_down(ss, o, 64);
  if ((tid & 63) == 0) red[tid >> 6] = ss;
  __syncthreads();
  if (tid == 0)
    red[4] = 1.f / sqrtf((red[0] + red[1] + red[2] + red[3]) * invN + 1e-6f);
  __syncthreads();
  const float sc = red[4];
  {
    f32x4 gg = *(const f32x4*)(g + tid * 4);
    f32x4 v = y0 * sc * gg;
#pragma unroll
    for (int k = 0; k < 4; ++k) v[k] = v[k] / (1.f + expf(-v[k]));
    *(f32x4*)(out + tid * 4) = v;
  }
  if (N == 2048) {
    f32x4 gg = *(const f32x4*)(g + 1024 + tid * 4);
    f32x4 v = y1 * sc * gg;
#pragma unroll
    for (int k = 0; k < 4; ++k) v[k] = v[k] / (1.f + expf(-v[k]));
    *(f32x4*)(out + 1024 + tid * 4) = v;
  }
}

DEVINL float sigm(float x) { return 1.f / (1.f + expf(-x)); }

// ---- x2 (action) pre-act + RMS + SiLU for row r, step tt ------------------
DEVINL void x2_row(const RPtrs& p, int tt, int r, float m, float* red) {
  const int tid = threadIdx.x;
  const int c0 = tid * 4;
  const float* arow = p.action + ((size_t)r * 64 + tt) * 16;
  f32x4 s2 = *(const f32x4*)(p.b_in_act + c0);
#pragma unroll
  for (int ii = 0; ii < 16; ++ii) {
    float av = arow[ii] * m;
    av = av / fmaxf(fabsf(av), 1.f);
    f32x4 wv = *(const f32x4*)(p.W_in_act + ii * 1024 + c0);
    FMA4(s2, av, wv);
  }
  float ss = s2[0]*s2[0] + s2[1]*s2[1] + s2[2]*s2[2] + s2[3]*s2[3];
#pragma unroll
  for (int o = 32; o > 0; o >>= 1) ss += __shfl_down(ss, o, 64);
  if ((tid & 63) == 0) red[tid >> 6] = ss;
  __syncthreads();
  if (tid == 0)
    red[4] = 1.f / sqrtf((red[0] + red[1] + red[2] + red[3]) * (1.f / 1024.f) + 1e-6f);
  __syncthreads();
  float sc = red[4];
  f32x4 gg = *(const f32x4*)(p.g_in_act + c0);
  f32x4 v = s2 * sc * gg;
#pragma unroll
  for (int k = 0; k < 4; ++k) v[k] = v[k] / (1.f + expf(-v[k]));
  *(f32x4*)(p.xact + (size_t)r * 3072 + 2048 + c0) = v;
}

// ===========================================================================
// K0: init state (zero deter + determ)
__global__ __launch_bounds__(256) void k_init(RPtrs p) {
  size_t i = (size_t)blockIdx.x * 256 + threadIdx.x;
  if (i < 65536) { p.deter[i] = 0.f; p.determ[i] = 0.f; }
}

// prologue x0(0): grid 64
__global__ __launch_bounds__(256, 2) void k_x0p(RPtrs p) {
  __shared__ __align__(16) float As[2304];
  int ct = blockIdx.x & 3, kc = blockIdx.x >> 2;
  LdPlain la{p.determ, 2048};
  gemm_tile<2>(la, p.W_in_deter, 1024, ct * 256, kc * 128,
               p.SX0 + (size_t)kc * 32768, 1024, ct * 256,
               kc == 0 ? p.b_in_deter : nullptr, As);
}

// prologue: x0fin (0-31) | x12(t=0) (32-63). grid 64
__global__ __launch_bounds__(256, 2) void k_profin(RPtrs p) {
  __shared__ float red[8];
  const int wg = blockIdx.x;
  const int tid = threadIdx.x;
  if (wg < 32) {
    act_fin(p.SX0, 1024, 16, wg, p.g_in_deter, p.xact + (size_t)wg * 3072,
            1.f / 1024.f, red);
  } else {
    const int r = wg - 32;
    const int c0 = tid * 4;
    // x1(0): stoch(-1)=0 -> pre = bias exactly
    f32x4 pre = *(const f32x4*)(p.b_in_stoch + c0);
    float ss = pre[0]*pre[0] + pre[1]*pre[1] + pre[2]*pre[2] + pre[3]*pre[3];
#pragma unroll
    for (int o = 32; o > 0; o >>= 1) ss += __shfl_down(ss, o, 64);
    if ((tid & 63) == 0) red[tid >> 6] = ss;
    __syncthreads();
    if (tid == 0)
      red[4] = 1.f / sqrtf((red[0] + red[1] + red[2] + red[3]) * (1.f / 1024.f) + 1e-6f);
    __syncthreads();
    float sc = red[4];
    f32x4 gg = *(const f32x4*)(p.g_in_stoch + c0);
    f32x4 v = pre * sc * gg;
#pragma unroll
    for (int k = 0; k < 4; ++k) v[k] = v[k] / (1.f + expf(-v[k]));
    *(f32x4*)(p.xact + (size_t)r * 3072 + 1024 + c0) = v;
    __syncthreads();
    float m = p.is_first[r * 64] ? 0.f : 1.f;
    x2_row(p, 0, r, m, red);
  }
}

// K1: dyn. grid 208
__global__ __launch_bounds__(256, 2) void k_dyn(RPtrs p, int t) {
  __shared__ __align__(16) float As[2304];
  const int wg = blockIdx.x;
  int blk = wg / 26, kc = wg % 26;  // KC=128
  LdDyn la{p.determ, p.xact, blk};
  gemm_tile<2>(la, p.W_dyn + (size_t)blk * 851968, 256, 0, kc * 128,
               p.SDyn + (size_t)kc * 65536, 2048, blk * 256,
               kc == 0 ? p.b_dyn + blk * 256 : nullptr, As);
}

// K2: dynfin. grid 32
__global__ __launch_bounds__(256, 2) void k_dynfin(RPtrs p) {
  __shared__ float red[8];
  act_fin(p.SDyn, 2048, 26, blockIdx.x, p.g_dyn,
          p.hact + (size_t)blockIdx.x * 2048, 1.f / 2048.f, red);
}

// K3: gru. grid 128
__global__ __launch_bounds__(256, 2) void k_gru(RPtrs p, int t) {
  __shared__ float Al[8704];
  const int wg = blockIdx.x;
  const int blk = wg >> 4, jch = wg & 15;
  const int tid = threadIdx.x;
  {
    const float* hp = p.hact + blk * 256 + tid;
#pragma unroll
    for (int jb = 0; jb < 32; ++jb)
      Al[tid * 34 + jb] = hp[(size_t)jb * 2048];
  }
  __syncthreads();
  const int j = tid & 15, rg = tid >> 4;
  const int r0 = rg * 2;
  const int jcol = jch * 16 + j;
  const float* Wg = p.W_gru + (size_t)blk * 196608 + jcol;
  float r0a = 0, r1a = 0, c0a = 0, c1a = 0, u0a = 0, u1a = 0;
#pragma unroll 4
  for (int kk = 0; kk < 256; ++kk) {
    float wr = Wg[(size_t)kk * 768];
    float wc = Wg[(size_t)kk * 768 + 256];
    float wu = Wg[(size_t)kk * 768 + 512];
    float ax = Al[kk * 34 + r0], ay = Al[kk * 34 + r0 + 1];
    r0a = fmaf(ax, wr, r0a); r1a = fmaf(ay, wr, r1a);
    c0a = fmaf(ax, wc, c0a); c1a = fmaf(ay, wc, c1a);
    u0a = fmaf(ax, wu, u0a); u1a = fmaf(ay, wu, u1a);
  }
  const int col = blk * 256 + jcol;
  const float br = p.b_gru[blk * 768 + jcol];
  const float bc = p.b_gru[blk * 768 + 256 + jcol];
  const float bu = p.b_gru[blk * 768 + 512 + jcol];
#pragma unroll
  for (int rr = 0; rr < 2; ++rr) {
    int r = r0 + rr;
    float gr = (rr ? r1a : r0a) + br;
    float gc = (rr ? c1a : c0a) + bc;
    float gu = (rr ? u1a : u0a) + bu;
    float rs = sigm(gr);
    float cc = tanhf(rs * gc);
    float uu = sigm(gu - 1.f);
    float dg = p.determ[(size_t)r * 2048 + col];
    float nd = uu * cc + (1.f - uu) * dg;
    p.deter[(size_t)r * 2048 + col] = nd;
    p.out_deters[((size_t)r * 64 + t) * 2048 + col] = nd;
    float mn = 0.f;
    if (t + 1 < 64) mn = p.is_first[r * 64 + (t + 1)] ? 0.f : 1.f;
    p.determ[(size_t)r * 2048 + col] = nd * mn;
  }
}

// K4: q0 (0-95) + x0(t+1) (96-159). grid 160
__global__ __launch_bounds__(256, 2) void k_q0x0(RPtrs p, int t) {
  __shared__ __align__(16) float As[2304];
  const int wg = blockIdx.x;
  if (wg < 96) {
    int ct = wg & 3, kc = wg >> 2;   // kc 0..23, KC=128, K=3072
    LdQ0 la{p.deter, p.embed, t};
    gemm_tile<2>(la, p.W_q0, 1024, ct * 256, kc * 128,
                 p.SQ0 + (size_t)kc * 32768, 1024, ct * 256,
                 kc == 0 ? p.b_q0 : nullptr, As);
  } else {
    if (t >= 63) return;
    int i = wg - 96, ct = i & 3, kc = i >> 2;   // kc 0..15, K=2048
    LdPlain la{p.determ, 2048};
    gemm_tile<2>(la, p.W_in_deter, 1024, ct * 256, kc * 128,
                 p.SX0 + (size_t)kc * 32768, 1024, ct * 256,
                 kc == 0 ? p.b_in_deter : nullptr, As);
  }
}

// K5: q0fin (0-31) + x0fin(t+1) (32-63). grid 64
__global__ __launch_bounds__(256, 2) void k_qfin(RPtrs p, int t) {
  __shared__ float red[8];
  const int wg = blockIdx.x;
  if (wg < 32)
    act_fin(p.SQ0, 1024, 24, wg, p.g_q0, p.q0act + (size_t)wg * 1024,
            1.f / 1024.f, red);
  else {
    if (t >= 63) return;
    act_fin(p.SX0, 1024, 16, wg - 32, p.g_in_deter,
            p.xact + (size_t)(wg - 32) * 3072, 1.f / 1024.f, red);
  }
}

// K6: qo. grid 64
__global__ __launch_bounds__(256, 2) void k_qo(RPtrs p, int t) {
  __shared__ __align__(16) float As[2304];
  int ct = blockIdx.x & 3, kc = blockIdx.x >> 2;   // kc 0..15, KC=64
  LdPlain la{p.q0act, 1024};
  gemm_tile<1>(la, p.W_qo, 1024, ct * 256, kc * 64,
               p.SQO + (size_t)kc * 32768, 1024, ct * 256,
               kc == 0 ? p.b_qo : nullptr, As);
}

// K7: qofin + argmax + x12(t+1). grid 32 (one WG per batch row)
__global__ __launch_bounds__(256, 2) void k_finx12(RPtrs p, int t) {
  __shared__ __align__(16) float ybuf[1024];
  __shared__ float red[8];
  __shared__ int sidx[32];
  const int r = blockIdx.x;
  const int tid = threadIdx.x;
  const float* b0 = p.SQO + (size_t)r * 1024 + tid * 4;
  f32x4 y = (f32x4){0.f, 0.f, 0.f, 0.f};
#pragma unroll
  for (int ch = 0; ch < 16; ++ch) y += *(const f32x4*)(b0 + (size_t)ch * 32768);
  *(f32x4*)(p.out_post + ((size_t)r * 64 + t) * 1024 + tid * 4) = y;
  *(f32x4*)(ybuf + tid * 4) = y;
  __syncthreads();
  if (tid < 32) {
    const float* rb = ybuf + tid * 32;
    float best = rb[0]; int bi = 0;
#pragma unroll
    for (int c = 1; c < 32; ++c) {
      float v = rb[c];
      if (v > best) { best = v; bi = c; }   // strict > keeps first index
    }
    sidx[tid] = bi;
  }
  __syncthreads();
  if (t >= 63) return;
  const float m = p.is_first[r * 64 + t + 1] ? 0.f : 1.f;
  const int c0 = tid * 4;
  // ---- x1(t+1): gather 32 one-hot rows of W_in_stoch
  f32x4 s1 = (f32x4){0.f, 0.f, 0.f, 0.f};
  if (m != 0.f) {
    for (int g = 0; g < 32; ++g)
      s1 += *(const f32x4*)(p.W_in_stoch + (size_t)(g * 32 + sidx[g]) * 1024 + c0);
  }
  f32x4 pre = *(const f32x4*)(p.b_in_stoch + c0) + s1 * m;
  float ss = pre[0]*pre[0] + pre[1]*pre[1] + pre[2]*pre[2] + pre[3]*pre[3];
#pragma unroll
  for (int o = 32; o > 0; o >>= 1) ss += __shfl_down(ss, o, 64);
  if ((tid & 63) == 0) red[tid >> 6] = ss;
  __syncthreads();
  if (tid == 0)
    red[4] = 1.f / sqrtf((red[0] + red[1] + red[2] + red[3]) * (1.f / 1024.f) + 1e-6f);
  __syncthreads();
  {
    float sc = red[4];
    f32x4 gg = *(const f32x4*)(p.g_in_stoch + c0);
    f32x4 v = pre * sc * gg;
#pragma unroll
    for (int k = 0; k < 4; ++k) v[k] = v[k] / (1.f + expf(-v[k]));
    *(f32x4*)(p.xact + (size_t)r * 3072 + 1024 + c0) = v;
  }
  __syncthreads();
  // ---- x2(t+1)
  x2_row(p, t + 1, r, m, red);
}

// ---- epilogue: batched prior over all 2048 (b,t) rows ---------------------
__global__ __launch_bounds__(256, 2) void kb_p0(RPtrs p) {
  __shared__ __align__(16) float As[2304];
  int rb = blockIdx.x >> 2, ct = blockIdx.x & 3;
  LdPlain la{p.out_deters + (size_t)rb * 32 * 2048, 2048};
  gemm_big(la, p.W_p0, 1024, ct * 256, 32,
           p.Abuf0 + (size_t)rb * 32 * 1024, 1024, p.b_p0, As);
}
__global__ __launch_bounds__(256, 2) void kb_fin0(RPtrs p) {
  __shared__ float red[8];
  int r = blockIdx.x;
  act_fin(p.Abuf0, 1024, 1, r, p.g_p0, p.Abuf1 + (size_t)r * 1024,
          1.f / 1024.f, red);
}
__global__ __launch_bounds__(256, 2) void kb_p1(RPtrs p) {
  __shared__ __align__(16) float As[2304];
  int rb = blockIdx.x >> 2, ct = blockIdx.x & 3;
  LdPlain la{p.Abuf1 + (size_t)rb * 32 * 1024, 1024};
  gemm_big(la, p.W_p1, 1024, ct * 256, 16,
           p.Abuf0 + (size_t)rb * 32 * 1024, 1024, p.b_p1, As);
}
__global__ __launch_bounds__(256, 2) void kb_fin1(RPtrs p) {
  __shared__ float red[8];
  int r = blockIdx.x;
  act_fin(p.Abuf0, 1024, 1, r, p.g_p1, p.Abuf1 + (size_t)r * 1024,
          1.f / 1024.f, red);
}
__global__ __launch_bounds__(256, 2) void kb_po(RPtrs p) {
  __shared__ __align__(16) float As[2304];
  int rb = blockIdx.x >> 2, ct = blockIdx.x & 3;
  LdPlain la{p.Abuf1 + (size_t)rb * 32 * 1024, 1024};
  gemm_big(la, p.W_po, 1024, ct * 256, 16,
           p.out_prior + (size_t)rb * 32 * 1024, 1024, p.b_po, As);
}

// ===========================================================================
extern "C" void kernel_launch(void* const* d_in, const int* in_sizes, int n_in,
                              void* d_out, int out_size, void* d_ws,
                              size_t ws_size, hipStream_t stream) {
  RPtrs p;
  p.embed      = (const float*)d_in[0];
  p.action     = (const float*)d_in[1];
  p.is_first   = (const int*)d_in[2];
  p.W_in_deter = (const float*)d_in[3];  p.b_in_deter = (const float*)d_in[4];  p.g_in_deter = (const float*)d_in[5];
  p.W_in_stoch = (const float*)d_in[6];  p.b_in_stoch = (const float*)d_in[7];  p.g_in_stoch = (const float*)d_in[8];
  p.W_in_act   = (const float*)d_in[9];  p.b_in_act   = (const float*)d_in[10]; p.g_in_act   = (const float*)d_in[11];
  p.W_dyn      = (const float*)d_in[12]; p.b_dyn      = (const float*)d_in[13]; p.g_dyn      = (const float*)d_in[14];
  p.W_gru      = (const float*)d_in[15]; p.b_gru      = (const float*)d_in[16];
  p.W_p0       = (const float*)d_in[17]; p.b_p0       = (const float*)d_in[18]; p.g_p0       = (const float*)d_in[19];
  p.W_p1       = (const float*)d_in[20]; p.b_p1       = (const float*)d_in[21]; p.g_p1       = (const float*)d_in[22];
  p.W_po       = (const float*)d_in[23]; p.b_po       = (const float*)d_in[24];
  p.W_q0       = (const float*)d_in[25]; p.b_q0       = (const float*)d_in[26]; p.g_q0       = (const float*)d_in[27];
  p.W_qo       = (const float*)d_in[28]; p.b_qo       = (const float*)d_in[29];

  float* o = (float*)d_out;
  p.out_post   = o;               // [32][64][1024]
  p.out_prior  = o + 2097152;     // [32][64][1024]
  p.out_deters = o + 4194304;     // [32][64][2048]

  float* w = (float*)d_ws;
  // loop-era layout (all dead by epilogue):
  p.deter  = w;                   // 65536
  p.determ = w + 65536;           // 65536
  p.xact   = w + 131072;          // 98304   [32][3072]
  p.hact   = w + 229376;          // 65536
  p.q0act  = w + 294912;          // 32768
  p.SDyn   = w + 393216;          // 1703936 [26][32][2048]
  p.SQ0    = w + 2097152;         // 786432  [24][32][1024]
  p.SX0    = w + 2883584;         // 524288  [16][32][1024]
  p.SQO    = w + 3407872;         // 524288  [16][32][1024]
  // epilogue-era layout (reuses everything):
  p.Abuf0  = w;                   // 2097152 [2048][1024]
  p.Abuf1  = w + 2097152;         // 2097152 [2048][1024]
  // total 4194304 floats = 16.8 MB (same footprint as R8)
  // NOTE: Abuf1 overlaps SQ0/SX0/SQO -- epilogue runs strictly after the
  // loop's last consumer (k_finx12 t=63), launch-ordered.

  k_init<<<512, 256, 0, stream>>>(p);
  k_x0p<<<64, 256, 0, stream>>>(p);
  k_profin<<<64, 256, 0, stream>>>(p);
  for (int t = 0; t < 64; ++t) {
    k_dyn<<<208, 256, 0, stream>>>(p, t);
    k_dynfin<<<32, 256, 0, stream>>>(p);
    k_gru<<<128, 256, 0, stream>>>(p, t);
    k_q0x0<<<160, 256, 0, stream>>>(p, t);
    k_qfin<<<64, 256, 0, stream>>>(p, t);
    k_qo<<<64, 256, 0, stream>>>(p, t);
    k_finx12<<<32, 256, 0, stream>>>(p, t);
  }
  kb_p0<<<256, 256, 0, stream>>>(p);
  kb_fin0<<<2048, 256, 0, stream>>>(p);
  kb_p1<<<256, 256, 0, stream>>>(p);
  kb_fin1<<<2048, 256, 0, stream>>>(p);
  kb_po<<<256, 256, 0, stream>>>(p);
}